// Round 6
// baseline (116.109 us; speedup 1.0000x reference)
//
#include <hip/hip_runtime.h>
#include <hip/hip_bf16.h>

#define D_ 256
#define H_ 8
#define B_ 2
#define S_ 2048
#define MTOT 4096
#define AUGQ 64          // q(32) + pq(16) + [maskbias](1) + pad(15)
#define NBH 16           // B_*H_
#define KPAD 72
#define NSPLIT 4
#define NJ 8             // key tiles (of 64) per split
#define LOG2E 1.4426950408889634f

typedef __attribute__((ext_vector_type(8))) short short8;
typedef __attribute__((ext_vector_type(4))) short short4v;
typedef __attribute__((ext_vector_type(4))) float f32x4;

static __device__ __forceinline__ short bf16_of(float f) {
  union { __hip_bfloat16 h; short s; } u;
  u.h = __float2bfloat16(f);
  return u.s;
}
static __device__ __forceinline__ float f_of_bf16(short s) {
  union { float f; unsigned int u; } u;
  u.u = ((unsigned int)(unsigned short)s) << 16;
  return u.f;
}

static __device__ __forceinline__ f32x4 mfma16(short4v a, short4v b, f32x4 c) {
#if defined(__has_builtin) && __has_builtin(__builtin_amdgcn_mfma_f32_16x16x16bf16_1k)
  return __builtin_amdgcn_mfma_f32_16x16x16bf16_1k(a, b, c, 0, 0, 0);
#else
  asm("v_mfma_f32_16x16x16_bf16 %0, %1, %2, %0" : "+v"(c) : "v"(a), "v"(b));
  return c;
#endif
}

// ---------------- fused prep: weights cvt/transpose + pq/pk fills ----------------

__global__ void prep_all(const float* __restrict__ Wq, const float* __restrict__ Wk,
                         const float* __restrict__ Wv, const float* __restrict__ Wo,
                         const float* __restrict__ coords, const int* __restrict__ mask,
                         const float* __restrict__ Wpq, const float* __restrict__ bpq,
                         const float* __restrict__ Wpk, const float* __restrict__ bpk,
                         short* __restrict__ Wqkv_t, short* __restrict__ Wo_t,
                         short* __restrict__ Qa, short* __restrict__ Ka,
                         short* __restrict__ VaT) {
  int gid = blockIdx.x * 256 + threadIdx.x;
  int NT = gridDim.x * 256;
  for (int idx = gid; idx < 768 * 256; idx += NT) {
    int n = idx >> 8, k = idx & 255;
    const float* W = (n < 256) ? Wq : (n < 512 ? Wk : Wv);
    Wqkv_t[idx] = bf16_of(W[k * 256 + (n & 255)]);
  }
  for (int idx = gid; idx < 256 * 256; idx += NT) {
    int n = idx >> 8, k = idx & 255;
    Wo_t[idx] = bf16_of(Wo[k * 256 + n]);
  }
  // pq/pk augmented cols (Q side pre-scaled by log2e for exp2 softmax)
  for (int idx = gid; idx < MTOT * 8; idx += NT) {
    int m = idx >> 3, h = idx & 7;
    int b = m >> 11, s = m & 2047;
    float r0 = coords[m * 9 + 3], r1 = coords[m * 9 + 4], r2 = coords[m * 9 + 5];
    size_t base = ((size_t)(b * 8 + h) * S_ + s) * AUGQ;
    short8 pqv[2], pkv[2];
#pragma unroll
    for (int c = 0; c < 2; c++)
#pragma unroll
      for (int i = 0; i < 8; i++) {
        int j = h * 16 + c * 8 + i;
        float pq = r0 * Wpq[j] + r1 * Wpq[128 + j] + r2 * Wpq[256 + j] + bpq[j];
        float pk = r0 * Wpk[j] + r1 * Wpk[128 + j] + r2 * Wpk[256 + j] + bpk[j];
        pqv[c][i] = bf16_of(pq * LOG2E);
        pkv[c][i] = bf16_of(pk * 0.25f);
      }
    short8 padq = {};
    padq[0] = bf16_of(LOG2E);  // multiplies Ka's mask-bias col
    short8 padk = {};
    padk[0] = mask[m] ? (short)0 : bf16_of(-1e9f);
    short8 z = {};
    *reinterpret_cast<short8*>(&Qa[base + 32]) = pqv[0];
    *reinterpret_cast<short8*>(&Qa[base + 40]) = pqv[1];
    *reinterpret_cast<short8*>(&Qa[base + 48]) = padq;
    *reinterpret_cast<short8*>(&Qa[base + 56]) = z;
    *reinterpret_cast<short8*>(&Ka[base + 32]) = pkv[0];
    *reinterpret_cast<short8*>(&Ka[base + 40]) = pkv[1];
    *reinterpret_cast<short8*>(&Ka[base + 48]) = padk;
    *reinterpret_cast<short8*>(&Ka[base + 56]) = z;
  }
  // pq (unscaled) into VaT (transposed layout [bh][32+p][s])
  for (int idx = gid; idx < NBH * 16 * (S_ / 8); idx += NT) {
    int s8 = idx & 255, p = (idx >> 8) & 15, bh = idx >> 12;
    int b = bh >> 3, h = bh & 7, j = h * 16 + p;
    float w0 = Wpq[j], w1 = Wpq[128 + j], w2 = Wpq[256 + j], bb = bpq[j];
    short8 o;
#pragma unroll
    for (int i = 0; i < 8; i++) {
      int m = b * 2048 + s8 * 8 + i;
      o[i] = bf16_of(coords[m * 9 + 3] * w0 + coords[m * 9 + 4] * w1 +
                     coords[m * 9 + 5] * w2 + bb);
    }
    *reinterpret_cast<short8*>(&VaT[((size_t)bh * 48 + 32 + p) * S_ + s8 * 8]) = o;
  }
}

// ---------------- QKV GEMM (M=4096, N=768, K=256), f32 input, vector epilogue ----------------

__global__ __launch_bounds__(256) void qkv_gemm(
    const float* __restrict__ X, const short* __restrict__ Wt,
    const float* __restrict__ bq, const float* __restrict__ bk, const float* __restrict__ bv,
    short* __restrict__ Qa, short* __restrict__ Ka, short* __restrict__ VaT) {
  __shared__ __align__(16) short As[64 * 136];
  __shared__ __align__(16) short Bs[64 * 136];
  int m0 = blockIdx.x * 64, n0 = blockIdx.y * 64;
  int tid = threadIdx.x, lane = tid & 63, w = tid >> 6;
  int t = lane & 15, g = lane >> 4, kf = g * 8;
  int wr = (w >> 1) * 32, wc = (w & 1) * 32;
  f32x4 acc[2][2] = {};
  int srow = tid >> 2, skc = (tid & 3) * 32;
  for (int ph = 0; ph < 2; ph++) {
    int k0 = ph * 128;
    __syncthreads();
    {
      const float* xs = &X[(size_t)(m0 + srow) * 256 + k0 + skc];
      short4v av[8];
#pragma unroll
      for (int i = 0; i < 8; i++) {
        f32x4 xv = *reinterpret_cast<const f32x4*>(&xs[i * 4]);
        short4v o;
        o[0] = bf16_of(xv[0]); o[1] = bf16_of(xv[1]);
        o[2] = bf16_of(xv[2]); o[3] = bf16_of(xv[3]);
        av[i] = o;
      }
#pragma unroll
      for (int i = 0; i < 8; i++)
        *reinterpret_cast<short4v*>(&As[srow * 136 + skc + i * 4]) = av[i];
      const uint4* wsrc = reinterpret_cast<const uint4*>(&Wt[(size_t)(n0 + srow) * 256 + k0 + skc]);
#pragma unroll
      for (int i = 0; i < 4; i++)
        *reinterpret_cast<uint4*>(&Bs[srow * 136 + skc + i * 8]) = wsrc[i];
    }
    __syncthreads();
#pragma unroll
    for (int kk = 0; kk < 4; kk++) {
      short8 a[2], bb[2];
#pragma unroll
      for (int i = 0; i < 2; i++)
        a[i] = *reinterpret_cast<const short8*>(&As[(wr + i * 16 + t) * 136 + kk * 32 + kf]);
#pragma unroll
      for (int jj = 0; jj < 2; jj++)
        bb[jj] = *reinterpret_cast<const short8*>(&Bs[(wc + jj * 16 + t) * 136 + kk * 32 + kf]);
#pragma unroll
      for (int i = 0; i < 2; i++)
#pragma unroll
        for (int jj = 0; jj < 2; jj++)
          acc[i][jj] = __builtin_amdgcn_mfma_f32_16x16x32_bf16(a[i], bb[jj], acc[i][jj], 0, 0, 0);
    }
  }
  // epilogue: bias/scale -> LDS bf16 tile -> vector stores
  __syncthreads();
  short* Cs = As;
  const float scale = 0.17677669529663687f * LOG2E;  // (1/sqrt(32)) * log2e
  int b = m0 >> 11, sbase = m0 & 2047;
#pragma unroll
  for (int i = 0; i < 2; i++)
#pragma unroll
    for (int jj = 0; jj < 2; jj++)
#pragma unroll
      for (int r = 0; r < 4; r++) {
        int rl = wr + i * 16 + g * 4 + r;
        int cl = wc + jj * 16 + t;
        int n = n0 + cl;
        float v = acc[i][jj][r];
        if (n < 256) v = (v + bq[n]) * scale;
        else if (n < 512) v = v + bk[n - 256];
        else v = v + bv[n - 512];
        Cs[rl * 72 + cl] = bf16_of(v);
      }
  __syncthreads();
  if (n0 < 512) {
#pragma unroll
    for (int i2 = 0; i2 < 2; i2++) {
      int task = tid + i2 * 256;
      int row = task >> 3, c = task & 7;
      int n = n0 + c * 8;
      short* dst = (n < 256) ? Qa : Ka;
      int nn = n & 255;
      int hh = nn >> 5, d = nn & 31;
      *reinterpret_cast<short8*>(&dst[((size_t)(b * 8 + hh) * S_ + sbase + row) * AUGQ + d]) =
          *reinterpret_cast<const short8*>(&Cs[row * 72 + c * 8]);
    }
  } else {
    int hv0 = (n0 - 512) >> 5;
#pragma unroll
    for (int i2 = 0; i2 < 2; i2++) {
      int task = tid + i2 * 256;
      int fl = task >> 3, s8 = task & 7;
      short8 o;
#pragma unroll
      for (int i = 0; i < 8; i++) o[i] = Cs[(s8 * 8 + i) * 72 + fl];
      int hh = hv0 + (fl >> 5), d = fl & 31;
      *reinterpret_cast<short8*>(&VaT[((size_t)(b * 8 + hh) * 48 + d) * S_ + sbase + s8 * 8]) = o;
    }
  }
}

// ---------------- flash attention: swapped QK^T, register P, K=16 PV ----------------
// 1-D grid 2048, XCD-swizzled; block 256 = 4 waves, each wave 16 queries.
// Single-buffer LDS: K @0 (9216B), V @9216 (6912B) = 16128B -> 8 blocks/CU.
// T14 staging: issue loads for tile j+1 before computing j; write after barrier.

__global__ __launch_bounds__(256, 8) void attn(
    const short* __restrict__ Qa, const short* __restrict__ Ka,
    const short* __restrict__ VaT,
    short* __restrict__ Ctx, float* __restrict__ AccL) {
  __shared__ __align__(16) char smem[16128];

  // XCD-aware decode: xcd = bid&7 owns 2 bh streams (all 4 splits) -> ~900KB L2-resident
  int bid = blockIdx.x;
  int xcd = bid & 7, slot = bid >> 3;       // slot 0..255
  int gidx = xcd * 8 + (slot >> 5);         // 0..63 = bhv*4+split
  int it = slot & 31;
  int split = gidx & 3;
  int bhv = gidx >> 2;

  int tid = threadIdx.x, lane = tid & 63, w = tid >> 6;
  int t = lane & 15, g = lane >> 4, kf = g * 8;
  int q0w = it * 64 + w * 16;
  size_t bh = (size_t)bhv * S_;

  short8 aq0 = *reinterpret_cast<const short8*>(&Qa[(bh + q0w + t) * AUGQ + kf]);
  short8 aq1 = *reinterpret_cast<const short8*>(&Qa[(bh + q0w + t) * AUGQ + 32 + kf]);

  f32x4 Oacc[3] = {};
  float lsum = 0.f;

  uint4 kreg0, kreg1, vreg0, vreg1;
  int srow = tid >> 3, sko = (tid & 7) * 8;
  const int jt0 = split * NJ;

  auto issue = [&](int jt) {
    const uint4* ks = reinterpret_cast<const uint4*>(&Ka[(bh + jt * 64) * AUGQ]);
    kreg0 = ks[tid];
    kreg1 = ks[tid + 256];
    size_t vb = (size_t)bhv * 48 * S_ + jt * 64;
    vreg0 = *reinterpret_cast<const uint4*>(&VaT[vb + (size_t)srow * S_ + sko]);
    if (tid < 128)
      vreg1 = *reinterpret_cast<const uint4*>(&VaT[vb + (size_t)(srow + 32) * S_ + sko]);
  };
  auto commit = [&]() {
    short* Kd = (short*)smem;
    short* Vd = (short*)(smem + 9216);
    *reinterpret_cast<uint4*>(&Kd[srow * KPAD + sko]) = kreg0;
    *reinterpret_cast<uint4*>(&Kd[(srow + 32) * KPAD + sko]) = kreg1;
    *reinterpret_cast<uint4*>(&Vd[srow * KPAD + sko]) = vreg0;
    if (tid < 128)
      *reinterpret_cast<uint4*>(&Vd[(srow + 32) * KPAD + sko]) = vreg1;
  };

  issue(jt0);
  commit();
  __syncthreads();

  const short* Kc = (const short*)smem;
  const short* Vc = (const short*)(smem + 9216);
  for (int j = 0; j < NJ; j++) {
    if (j + 1 < NJ) issue(jt0 + j + 1);
    short4v pb[4];
#pragma unroll
    for (int sub = 0; sub < 4; sub++) {
      short8 ka0 = *reinterpret_cast<const short8*>(&Kc[(sub * 16 + t) * KPAD + kf]);
      short8 ka1 = *reinterpret_cast<const short8*>(&Kc[(sub * 16 + t) * KPAD + 32 + kf]);
      f32x4 s0 = {};
      s0 = __builtin_amdgcn_mfma_f32_16x16x32_bf16(ka0, aq0, s0, 0, 0, 0);
      s0 = __builtin_amdgcn_mfma_f32_16x16x32_bf16(ka1, aq1, s0, 0, 0, 0);
      float p0 = exp2f(s0[0]);
      float p1 = exp2f(s0[1]);
      float p2 = exp2f(s0[2]);
      float p3 = exp2f(s0[3]);
      lsum += (p0 + p1) + (p2 + p3);
      short4v pk4;
      pk4[0] = bf16_of(p0); pk4[1] = bf16_of(p1);
      pk4[2] = bf16_of(p2); pk4[3] = bf16_of(p3);
      pb[sub] = pk4;
    }
    __builtin_amdgcn_s_setprio(1);
#pragma unroll
    for (int tt = 0; tt < 3; tt++) {
#pragma unroll
      for (int sub = 0; sub < 4; sub++) {
        short4v va = *reinterpret_cast<const short4v*>(&Vc[(tt * 16 + t) * KPAD + sub * 16 + g * 4]);
        Oacc[tt] = mfma16(va, pb[sub], Oacc[tt]);
      }
    }
    __builtin_amdgcn_s_setprio(0);
    __syncthreads();
    if (j + 1 < NJ) {
      commit();
      __syncthreads();
    }
  }

  // epilogue: reduce lsum across g-groups; transpose O via LDS; bf16 partial ctx out
  lsum += __shfl_xor(lsum, 16);
  lsum += __shfl_xor(lsum, 32);

  float* Of = (float*)smem;  // 64 x 52 f32 overlay (13312B)
#pragma unroll
  for (int tt = 0; tt < 3; tt++)
#pragma unroll
    for (int r = 0; r < 4; r++)
      Of[(w * 16 + t) * 52 + tt * 16 + g * 4 + r] = Oacc[tt][r];
  if (lane < 16) AccL[(size_t)(split * NBH + bhv) * S_ + q0w + lane] = lsum;
  __syncthreads();
  short* CtxP = Ctx + (size_t)split * NBH * S_ * 48;
  size_t obase = bh + it * 64;
  for (int task = tid; task < 384; task += 256) {
    int row = task / 6, c8 = task % 6;
    const float* src = &Of[row * 52 + c8 * 8];
    short8 o;
#pragma unroll
    for (int i = 0; i < 8; i++) o[i] = bf16_of(src[i]);
    *reinterpret_cast<short8*>(&CtxP[(obase + row) * 48 + c8 * 8]) = o;
  }
}

// ---------------- output projection with fused bf16 4-way split-merge ----------------
// grid (64, 4), 512 threads (8 waves)

__global__ __launch_bounds__(512) void out_gemm(
    const short* __restrict__ Ctx, const float* __restrict__ AccL,
    const short* __restrict__ Wot, const float* __restrict__ bo,
    float* __restrict__ Out) {
  __shared__ __align__(16) short As[64 * 136];
  __shared__ __align__(16) short Bs[64 * 136];
  const size_t CTXSZ = (size_t)NBH * S_ * 48;
  int m0 = blockIdx.x * 64, n0 = blockIdx.y * 64;
  int tid = threadIdx.x, lane = tid & 63, w = tid >> 6;
  int t = lane & 15, g = lane >> 4, kf = g * 8;
  int wm = w & 3, wn = w >> 2;
  int b = m0 >> 11, sbase = m0 & 2047;
  f32x4 acc[2] = {};
  int srow = tid >> 3, skc = (tid & 7) * 16;
  for (int ph = 0; ph < 2; ph++) {
    int k0 = ph * 128;
    __syncthreads();
    {
      int kg = k0 + skc;
      int hh = kg >> 5, d0 = kg & 31;
      size_t rowO = (size_t)(b * 8 + hh) * S_ + sbase + srow;
      float l = 0.f;
#pragma unroll
      for (int sp = 0; sp < NSPLIT; sp++) l += AccL[(size_t)sp * NBH * S_ + rowO];
      float inv = 1.0f / l;
#pragma unroll
      for (int half = 0; half < 2; half++) {
        float sum[8] = {};
#pragma unroll
        for (int sp = 0; sp < NSPLIT; sp++) {
          short8 a = *reinterpret_cast<const short8*>(&Ctx[sp * CTXSZ + rowO * 48 + d0 + half * 8]);
#pragma unroll
          for (int c = 0; c < 8; c++) sum[c] += f_of_bf16(a[c]);
        }
        short8 o;
#pragma unroll
        for (int c = 0; c < 8; c++) o[c] = bf16_of(sum[c] * inv);
        *reinterpret_cast<short8*>(&As[srow * 136 + skc + half * 8]) = o;
      }
      *reinterpret_cast<uint4*>(&Bs[srow * 136 + skc]) =
          *reinterpret_cast<const uint4*>(&Wot[(size_t)(n0 + srow) * 256 + kg]);
      *reinterpret_cast<uint4*>(&Bs[srow * 136 + skc + 8]) =
          *reinterpret_cast<const uint4*>(&Wot[(size_t)(n0 + srow) * 256 + kg + 8]);
    }
    __syncthreads();
#pragma unroll
    for (int kk = 0; kk < 4; kk++) {
      short8 a = *reinterpret_cast<const short8*>(&As[(wm * 16 + t) * 136 + kk * 32 + kf]);
#pragma unroll
      for (int jj = 0; jj < 2; jj++) {
        short8 bb = *reinterpret_cast<const short8*>(&Bs[(wn * 32 + jj * 16 + t) * 136 + kk * 32 + kf]);
        acc[jj] = __builtin_amdgcn_mfma_f32_16x16x32_bf16(a, bb, acc[jj], 0, 0, 0);
      }
    }
  }
#pragma unroll
  for (int jj = 0; jj < 2; jj++)
#pragma unroll
    for (int r = 0; r < 4; r++) {
      int mrow = m0 + wm * 16 + g * 4 + r;
      int n = n0 + wn * 32 + jj * 16 + t;
      Out[(size_t)mrow * 256 + n] = acc[jj][r] + bo[n];
    }
}

// ---------------- point projection with fused bf16 4-way split-merge ----------------
// 4 threads per output row; grid 64 x 256

__global__ void point_proj(const short* __restrict__ Ctx, const float* __restrict__ AccL,
                           const float* __restrict__ Wpo, const float* __restrict__ bpo,
                           float* __restrict__ out) {
  const size_t CTXSZ = (size_t)NBH * S_ * 48;
  int gid = blockIdx.x * 256 + threadIdx.x;
  int m = gid >> 2, qr = gid & 3;
  int b = m >> 11, s = m & 2047;
  float a0 = 0.f, a1 = 0.f, a2 = 0.f;
#pragma unroll
  for (int h2 = 0; h2 < 2; h2++) {
    int hh = qr * 2 + h2;
    size_t rowO = (size_t)(b * 8 + hh) * S_ + s;
    float l = 0.f;
#pragma unroll
    for (int sp = 0; sp < NSPLIT; sp++) l += AccL[(size_t)sp * NBH * S_ + rowO];
    float inv = 1.0f / l;
#pragma unroll
    for (int half = 0; half < 2; half++) {
      float sum[8] = {};
#pragma unroll
      for (int sp = 0; sp < NSPLIT; sp++) {
        short8 v = *reinterpret_cast<const short8*>(&Ctx[sp * CTXSZ + rowO * 48 + 32 + half * 8]);
#pragma unroll
        for (int c = 0; c < 8; c++) sum[c] += f_of_bf16(v[c]);
      }
#pragma unroll
      for (int c = 0; c < 8; c++) {
        float val = sum[c] * inv;
        int j = hh * 16 + half * 8 + c;
        a0 += val * Wpo[j * 3 + 0];
        a1 += val * Wpo[j * 3 + 1];
        a2 += val * Wpo[j * 3 + 2];
      }
    }
  }
  a0 += __shfl_xor(a0, 1); a0 += __shfl_xor(a0, 2);
  a1 += __shfl_xor(a1, 1); a1 += __shfl_xor(a1, 2);
  a2 += __shfl_xor(a2, 1); a2 += __shfl_xor(a2, 2);
  if (qr == 0) {
    out[(size_t)m * 3 + 0] = a0 + bpo[0];
    out[(size_t)m * 3 + 1] = a1 + bpo[1];
    out[(size_t)m * 3 + 2] = a2 + bpo[2];
  }
}

// ---------------- launch ----------------

extern "C" void kernel_launch(void* const* d_in, const int* in_sizes, int n_in,
                              void* d_out, int out_size, void* d_ws, size_t ws_size,
                              hipStream_t stream) {
  const float* seq    = (const float*)d_in[0];
  const float* coords = (const float*)d_in[1];
  const int*   mask   = (const int*)d_in[3];
  const float* Wq  = (const float*)d_in[4];
  const float* bq  = (const float*)d_in[5];
  const float* Wk  = (const float*)d_in[6];
  const float* bk  = (const float*)d_in[7];
  const float* Wv  = (const float*)d_in[8];
  const float* bv  = (const float*)d_in[9];
  const float* Wpq = (const float*)d_in[10];
  const float* bpq = (const float*)d_in[11];
  const float* Wpk = (const float*)d_in[12];
  const float* bpk = (const float*)d_in[13];
  const float* Wo  = (const float*)d_in[14];
  const float* bo  = (const float*)d_in[15];
  const float* Wpo = (const float*)d_in[16];
  const float* bpo = (const float*)d_in[17];
  float* out = (float*)d_out;

  char* ws = (char*)d_ws;
  short* Wqkv_t = (short*)ws; ws += 768 * 256 * 2;
  short* Wo_t   = (short*)ws; ws += 256 * 256 * 2;
  short* Qa     = (short*)ws; ws += (size_t)NBH * S_ * AUGQ * 2;
  short* Ka     = (short*)ws; ws += (size_t)NBH * S_ * AUGQ * 2;
  short* VaT    = (short*)ws; ws += (size_t)NBH * 48 * S_ * 2;
  short* Ctx    = (short*)ws; ws += (size_t)NSPLIT * NBH * S_ * 48 * 2;
  float* AccL   = (float*)ws; ws += (size_t)NSPLIT * NBH * S_ * 4;

  prep_all<<<1024, 256, 0, stream>>>(Wq, Wk, Wv, Wo, coords, mask, Wpq, bpq, Wpk, bpk,
                                     Wqkv_t, Wo_t, Qa, Ka, VaT);
  qkv_gemm<<<dim3(64, 12), 256, 0, stream>>>(seq, Wqkv_t, bq, bk, bv, Qa, Ka, VaT);
  attn<<<2048, 256, 0, stream>>>(Qa, Ka, VaT, Ctx, AccL);
  out_gemm<<<dim3(64, 4), 512, 0, stream>>>(Ctx, AccL, Wo_t, bo, out);
  point_proj<<<64, 256, 0, stream>>>(Ctx, AccL, Wpo, bpo, out + (size_t)MTOT * 256);
}

// Round 7
// 69.519 us; speedup vs baseline: 1.6702x; 1.6702x over previous
//
#include <hip/hip_runtime.h>
#include <hip/hip_bf16.h>

#define D_ 256
#define H_ 8
#define B_ 2
#define S_ 2048
#define MTOT 4096
#define AUGQ 64          // q(32) + pq(16) + [maskbias](1) + pad(15)
#define NBH 16           // B_*H_
#define KPAD 72
#define NSPLIT 2
#define NJ 16            // key tiles (of 64) per split
#define LOG2E 1.4426950408889634f

typedef __attribute__((ext_vector_type(8))) short short8;
typedef __attribute__((ext_vector_type(4))) short short4v;
typedef __attribute__((ext_vector_type(4))) float f32x4;

static __device__ __forceinline__ short bf16_of(float f) {
  union { __hip_bfloat16 h; short s; } u;
  u.h = __float2bfloat16(f);
  return u.s;
}
static __device__ __forceinline__ float f_of_bf16(short s) {
  union { float f; unsigned int u; } u;
  u.u = ((unsigned int)(unsigned short)s) << 16;
  return u.f;
}

static __device__ __forceinline__ f32x4 mfma16(short4v a, short4v b, f32x4 c) {
#if defined(__has_builtin) && __has_builtin(__builtin_amdgcn_mfma_f32_16x16x16bf16_1k)
  return __builtin_amdgcn_mfma_f32_16x16x16bf16_1k(a, b, c, 0, 0, 0);
#else
  asm("v_mfma_f32_16x16x16_bf16 %0, %1, %2, %0" : "+v"(c) : "v"(a), "v"(b));
  return c;
#endif
}

// ---------------- fused prep: weights cvt/transpose + pq/pk fills ----------------

__global__ void prep_all(const float* __restrict__ Wq, const float* __restrict__ Wk,
                         const float* __restrict__ Wv, const float* __restrict__ Wo,
                         const float* __restrict__ coords, const int* __restrict__ mask,
                         const float* __restrict__ Wpq, const float* __restrict__ bpq,
                         const float* __restrict__ Wpk, const float* __restrict__ bpk,
                         short* __restrict__ Wqkv_t, short* __restrict__ Wo_t,
                         short* __restrict__ Qa, short* __restrict__ Ka,
                         short* __restrict__ VaT) {
  int gid = blockIdx.x * 256 + threadIdx.x;
  int NT = gridDim.x * 256;
  for (int idx = gid; idx < 768 * 256; idx += NT) {
    int n = idx >> 8, k = idx & 255;
    const float* W = (n < 256) ? Wq : (n < 512 ? Wk : Wv);
    Wqkv_t[idx] = bf16_of(W[k * 256 + (n & 255)]);
  }
  for (int idx = gid; idx < 256 * 256; idx += NT) {
    int n = idx >> 8, k = idx & 255;
    Wo_t[idx] = bf16_of(Wo[k * 256 + n]);
  }
  // pq/pk augmented cols (Q side pre-scaled by log2e for exp2 softmax)
  for (int idx = gid; idx < MTOT * 8; idx += NT) {
    int m = idx >> 3, h = idx & 7;
    int b = m >> 11, s = m & 2047;
    float r0 = coords[m * 9 + 3], r1 = coords[m * 9 + 4], r2 = coords[m * 9 + 5];
    size_t base = ((size_t)(b * 8 + h) * S_ + s) * AUGQ;
    short8 pqv[2], pkv[2];
#pragma unroll
    for (int c = 0; c < 2; c++)
#pragma unroll
      for (int i = 0; i < 8; i++) {
        int j = h * 16 + c * 8 + i;
        float pq = r0 * Wpq[j] + r1 * Wpq[128 + j] + r2 * Wpq[256 + j] + bpq[j];
        float pk = r0 * Wpk[j] + r1 * Wpk[128 + j] + r2 * Wpk[256 + j] + bpk[j];
        pqv[c][i] = bf16_of(pq * LOG2E);
        pkv[c][i] = bf16_of(pk * 0.25f);
      }
    short8 padq = {};
    padq[0] = bf16_of(LOG2E);  // multiplies Ka's mask-bias col
    short8 padk = {};
    padk[0] = mask[m] ? (short)0 : bf16_of(-1e9f);
    short8 z = {};
    *reinterpret_cast<short8*>(&Qa[base + 32]) = pqv[0];
    *reinterpret_cast<short8*>(&Qa[base + 40]) = pqv[1];
    *reinterpret_cast<short8*>(&Qa[base + 48]) = padq;
    *reinterpret_cast<short8*>(&Qa[base + 56]) = z;
    *reinterpret_cast<short8*>(&Ka[base + 32]) = pkv[0];
    *reinterpret_cast<short8*>(&Ka[base + 40]) = pkv[1];
    *reinterpret_cast<short8*>(&Ka[base + 48]) = padk;
    *reinterpret_cast<short8*>(&Ka[base + 56]) = z;
  }
  // pq (unscaled) into VaT (transposed layout [bh][32+p][s])
  for (int idx = gid; idx < NBH * 16 * (S_ / 8); idx += NT) {
    int s8 = idx & 255, p = (idx >> 8) & 15, bh = idx >> 12;
    int b = bh >> 3, h = bh & 7, j = h * 16 + p;
    float w0 = Wpq[j], w1 = Wpq[128 + j], w2 = Wpq[256 + j], bb = bpq[j];
    short8 o;
#pragma unroll
    for (int i = 0; i < 8; i++) {
      int m = b * 2048 + s8 * 8 + i;
      o[i] = bf16_of(coords[m * 9 + 3] * w0 + coords[m * 9 + 4] * w1 +
                     coords[m * 9 + 5] * w2 + bb);
    }
    *reinterpret_cast<short8*>(&VaT[((size_t)bh * 48 + 32 + p) * S_ + s8 * 8]) = o;
  }
}

// ---------------- QKV GEMM (M=4096, N=768, K=256), f32 input, vector epilogue ----------------

__global__ __launch_bounds__(256) void qkv_gemm(
    const float* __restrict__ X, const short* __restrict__ Wt,
    const float* __restrict__ bq, const float* __restrict__ bk, const float* __restrict__ bv,
    short* __restrict__ Qa, short* __restrict__ Ka, short* __restrict__ VaT) {
  __shared__ __align__(16) short As[64 * 136];
  __shared__ __align__(16) short Bs[64 * 136];
  int m0 = blockIdx.x * 64, n0 = blockIdx.y * 64;
  int tid = threadIdx.x, lane = tid & 63, w = tid >> 6;
  int t = lane & 15, g = lane >> 4, kf = g * 8;
  int wr = (w >> 1) * 32, wc = (w & 1) * 32;
  f32x4 acc[2][2] = {};
  int srow = tid >> 2, skc = (tid & 3) * 32;
  for (int ph = 0; ph < 2; ph++) {
    int k0 = ph * 128;
    __syncthreads();
    {
      const float* xs = &X[(size_t)(m0 + srow) * 256 + k0 + skc];
      short4v av[8];
#pragma unroll
      for (int i = 0; i < 8; i++) {
        f32x4 xv = *reinterpret_cast<const f32x4*>(&xs[i * 4]);
        short4v o;
        o[0] = bf16_of(xv[0]); o[1] = bf16_of(xv[1]);
        o[2] = bf16_of(xv[2]); o[3] = bf16_of(xv[3]);
        av[i] = o;
      }
#pragma unroll
      for (int i = 0; i < 8; i++)
        *reinterpret_cast<short4v*>(&As[srow * 136 + skc + i * 4]) = av[i];
      const uint4* wsrc = reinterpret_cast<const uint4*>(&Wt[(size_t)(n0 + srow) * 256 + k0 + skc]);
#pragma unroll
      for (int i = 0; i < 4; i++)
        *reinterpret_cast<uint4*>(&Bs[srow * 136 + skc + i * 8]) = wsrc[i];
    }
    __syncthreads();
#pragma unroll
    for (int kk = 0; kk < 4; kk++) {
      short8 a[2], bb[2];
#pragma unroll
      for (int i = 0; i < 2; i++)
        a[i] = *reinterpret_cast<const short8*>(&As[(wr + i * 16 + t) * 136 + kk * 32 + kf]);
#pragma unroll
      for (int jj = 0; jj < 2; jj++)
        bb[jj] = *reinterpret_cast<const short8*>(&Bs[(wc + jj * 16 + t) * 136 + kk * 32 + kf]);
#pragma unroll
      for (int i = 0; i < 2; i++)
#pragma unroll
        for (int jj = 0; jj < 2; jj++)
          acc[i][jj] = __builtin_amdgcn_mfma_f32_16x16x32_bf16(a[i], bb[jj], acc[i][jj], 0, 0, 0);
    }
  }
  // epilogue: bias/scale -> LDS bf16 tile -> vector stores
  __syncthreads();
  short* Cs = As;
  const float scale = 0.17677669529663687f * LOG2E;  // (1/sqrt(32)) * log2e
  int b = m0 >> 11, sbase = m0 & 2047;
#pragma unroll
  for (int i = 0; i < 2; i++)
#pragma unroll
    for (int jj = 0; jj < 2; jj++)
#pragma unroll
      for (int r = 0; r < 4; r++) {
        int rl = wr + i * 16 + g * 4 + r;
        int cl = wc + jj * 16 + t;
        int n = n0 + cl;
        float v = acc[i][jj][r];
        if (n < 256) v = (v + bq[n]) * scale;
        else if (n < 512) v = v + bk[n - 256];
        else v = v + bv[n - 512];
        Cs[rl * 72 + cl] = bf16_of(v);
      }
  __syncthreads();
  if (n0 < 512) {
#pragma unroll
    for (int i2 = 0; i2 < 2; i2++) {
      int task = tid + i2 * 256;
      int row = task >> 3, c = task & 7;
      int n = n0 + c * 8;
      short* dst = (n < 256) ? Qa : Ka;
      int nn = n & 255;
      int hh = nn >> 5, d = nn & 31;
      *reinterpret_cast<short8*>(&dst[((size_t)(b * 8 + hh) * S_ + sbase + row) * AUGQ + d]) =
          *reinterpret_cast<const short8*>(&Cs[row * 72 + c * 8]);
    }
  } else {
    int hv0 = (n0 - 512) >> 5;
#pragma unroll
    for (int i2 = 0; i2 < 2; i2++) {
      int task = tid + i2 * 256;
      int fl = task >> 3, s8 = task & 7;
      short8 o;
#pragma unroll
      for (int i = 0; i < 8; i++) o[i] = Cs[(s8 * 8 + i) * 72 + fl];
      int hh = hv0 + (fl >> 5), d = fl & 31;
      *reinterpret_cast<short8*>(&VaT[((size_t)(b * 8 + hh) * 48 + d) * S_ + sbase + s8 * 8]) = o;
    }
  }
}

// ---------------- flash attention: swapped QK^T, register P, 32 queries/wave ----------------
// grid 512 (XCD-swizzled); block 256 = 4 waves, each wave 32 queries (2 col-groups
// sharing K/V fragments -> half the LDS reads per query). Double-buffered LDS,
// one barrier per iter. LDS: Kb0 @0 (9216B), Kb1 @9216, Vb0 @18432 (6912B),
// Vb1 @25344 = 32256B. Epilogue overlays Of (128 x 52 f32 = 26624B) at 0.

__global__ __launch_bounds__(256, 2) void attn(
    const short* __restrict__ Qa, const short* __restrict__ Ka,
    const short* __restrict__ VaT,
    short* __restrict__ Ctx, float* __restrict__ AccL) {
  __shared__ __align__(16) char smem[32256];

  // XCD decode: xcd = bid&7 owns 2 bh streams (~900KB KV, L2-resident)
  int bid = blockIdx.x;
  int xcd = bid & 7, slot = bid >> 3;       // slot 0..63
  int gidx = xcd * 4 + (slot >> 4);         // 0..31 = bhv*2+split
  int it = slot & 15;
  int split = gidx & 1;
  int bhv = gidx >> 1;

  int tid = threadIdx.x, lane = tid & 63, w = tid >> 6;
  int t = lane & 15, g = lane >> 4, kf = g * 8;
  int q0w = it * 128 + w * 32;
  size_t bh = (size_t)bhv * S_;

  short8 aq[2][2];
#pragma unroll
  for (int g2 = 0; g2 < 2; g2++)
#pragma unroll
    for (int c = 0; c < 2; c++)
      aq[g2][c] = *reinterpret_cast<const short8*>(
          &Qa[(bh + q0w + g2 * 16 + t) * AUGQ + c * 32 + kf]);

  f32x4 OaccA[3] = {}, OaccB[3] = {};
  float lsum0 = 0.f, lsum1 = 0.f;

  uint4 kreg0, kreg1, vreg0, vreg1;
  int srow = tid >> 3, sko = (tid & 7) * 8;
  const int jt0 = split * NJ;

  auto issue = [&](int jt) {
    const uint4* ks = reinterpret_cast<const uint4*>(&Ka[(bh + jt * 64) * AUGQ]);
    kreg0 = ks[tid];
    kreg1 = ks[tid + 256];
    size_t vb = (size_t)bhv * 48 * S_ + jt * 64;
    vreg0 = *reinterpret_cast<const uint4*>(&VaT[vb + (size_t)srow * S_ + sko]);
    if (tid < 128)
      vreg1 = *reinterpret_cast<const uint4*>(&VaT[vb + (size_t)(srow + 32) * S_ + sko]);
  };
  auto commit = [&](int buf) {
    short* Kd = (short*)(smem + buf * 9216);
    short* Vd = (short*)(smem + 18432 + buf * 6912);
    *reinterpret_cast<uint4*>(&Kd[srow * KPAD + sko]) = kreg0;
    *reinterpret_cast<uint4*>(&Kd[(srow + 32) * KPAD + sko]) = kreg1;
    *reinterpret_cast<uint4*>(&Vd[srow * KPAD + sko]) = vreg0;
    if (tid < 128)
      *reinterpret_cast<uint4*>(&Vd[(srow + 32) * KPAD + sko]) = vreg1;
  };

  issue(jt0);
  commit(0);
  __syncthreads();

  for (int j = 0; j < NJ; j++) {
    int cur = j & 1;
    if (j + 1 < NJ) issue(jt0 + j + 1);
    const short* Kc = (const short*)(smem + cur * 9216);
    const short* Vc = (const short*)(smem + 18432 + cur * 6912);
    short4v pbA[4], pbB[4];
#pragma unroll
    for (int sub = 0; sub < 4; sub++) {
      short8 ka0 = *reinterpret_cast<const short8*>(&Kc[(sub * 16 + t) * KPAD + kf]);
      short8 ka1 = *reinterpret_cast<const short8*>(&Kc[(sub * 16 + t) * KPAD + 32 + kf]);
      f32x4 sA = {}, sB = {};
      sA = __builtin_amdgcn_mfma_f32_16x16x32_bf16(ka0, aq[0][0], sA, 0, 0, 0);
      sA = __builtin_amdgcn_mfma_f32_16x16x32_bf16(ka1, aq[0][1], sA, 0, 0, 0);
      sB = __builtin_amdgcn_mfma_f32_16x16x32_bf16(ka0, aq[1][0], sB, 0, 0, 0);
      sB = __builtin_amdgcn_mfma_f32_16x16x32_bf16(ka1, aq[1][1], sB, 0, 0, 0);
      float a0 = exp2f(sA[0]), a1 = exp2f(sA[1]), a2 = exp2f(sA[2]), a3 = exp2f(sA[3]);
      float b0 = exp2f(sB[0]), b1 = exp2f(sB[1]), b2 = exp2f(sB[2]), b3 = exp2f(sB[3]);
      lsum0 += (a0 + a1) + (a2 + a3);
      lsum1 += (b0 + b1) + (b2 + b3);
      short4v pa, pb;
      pa[0] = bf16_of(a0); pa[1] = bf16_of(a1); pa[2] = bf16_of(a2); pa[3] = bf16_of(a3);
      pb[0] = bf16_of(b0); pb[1] = bf16_of(b1); pb[2] = bf16_of(b2); pb[3] = bf16_of(b3);
      pbA[sub] = pa; pbB[sub] = pb;
    }
    __builtin_amdgcn_s_setprio(1);
#pragma unroll
    for (int tt = 0; tt < 3; tt++) {
#pragma unroll
      for (int sub = 0; sub < 4; sub++) {
        short4v va = *reinterpret_cast<const short4v*>(&Vc[(tt * 16 + t) * KPAD + sub * 16 + g * 4]);
        OaccA[tt] = mfma16(va, pbA[sub], OaccA[tt]);
        OaccB[tt] = mfma16(va, pbB[sub], OaccB[tt]);
      }
    }
    __builtin_amdgcn_s_setprio(0);
    if (j + 1 < NJ) commit(cur ^ 1);
    __syncthreads();
  }

  // epilogue: reduce lsums; transpose O via LDS overlay; bf16 partial ctx out
  lsum0 += __shfl_xor(lsum0, 16); lsum0 += __shfl_xor(lsum0, 32);
  lsum1 += __shfl_xor(lsum1, 16); lsum1 += __shfl_xor(lsum1, 32);

  float* Of = (float*)smem;  // 128 x 52 f32 overlay
#pragma unroll
  for (int tt = 0; tt < 3; tt++)
#pragma unroll
    for (int r = 0; r < 4; r++) {
      Of[(w * 32 + t) * 52 + tt * 16 + g * 4 + r] = OaccA[tt][r];
      Of[(w * 32 + 16 + t) * 52 + tt * 16 + g * 4 + r] = OaccB[tt][r];
    }
  if (lane < 16) {
    size_t lb = (size_t)(split * NBH + bhv) * S_ + q0w + lane;
    AccL[lb] = lsum0;
    AccL[lb + 16] = lsum1;
  }
  __syncthreads();
  short* CtxP = Ctx + (size_t)split * NBH * S_ * 48;
  size_t obase = bh + it * 128;
  for (int task = tid; task < 768; task += 256) {
    int row = task / 6, c8 = task % 6;
    const float* src = &Of[row * 52 + c8 * 8];
    short8 o;
#pragma unroll
    for (int i = 0; i < 8; i++) o[i] = bf16_of(src[i]);
    *reinterpret_cast<short8*>(&CtxP[(obase + row) * 48 + c8 * 8]) = o;
  }
}

// ---------------- output projection + fused split-merge + fused point_proj ----------------
// grid (64, 5), 512 threads. y<4: seq_out GEMM n-slice. y==4: point_out.

__global__ __launch_bounds__(512) void out_gemm(
    const short* __restrict__ Ctx, const float* __restrict__ AccL,
    const short* __restrict__ Wot, const float* __restrict__ bo,
    const float* __restrict__ Wpo, const float* __restrict__ bpo,
    float* __restrict__ Out) {
  const size_t CTXSZ = (size_t)NBH * S_ * 48;
  int m0 = blockIdx.x * 64;
  int tid = threadIdx.x;
  int b = m0 >> 11, sbase = m0 & 2047;

  if (blockIdx.y == 4) {
    // point_out: 8 threads per row, one head each
    int row = tid >> 3, hh = tid & 7;
    int m = m0 + row, s = sbase + row;
    size_t rowO = (size_t)(b * 8 + hh) * S_ + s;
    float inv = 1.0f / (AccL[rowO] + AccL[(size_t)NBH * S_ + rowO]);
    float a0 = 0.f, a1 = 0.f, a2 = 0.f;
#pragma unroll
    for (int half = 0; half < 2; half++) {
      short8 v0 = *reinterpret_cast<const short8*>(&Ctx[rowO * 48 + 32 + half * 8]);
      short8 v1 = *reinterpret_cast<const short8*>(&Ctx[CTXSZ + rowO * 48 + 32 + half * 8]);
#pragma unroll
      for (int c = 0; c < 8; c++) {
        float val = (f_of_bf16(v0[c]) + f_of_bf16(v1[c])) * inv;
        int j = hh * 16 + half * 8 + c;
        a0 += val * Wpo[j * 3 + 0];
        a1 += val * Wpo[j * 3 + 1];
        a2 += val * Wpo[j * 3 + 2];
      }
    }
    a0 += __shfl_xor(a0, 1); a0 += __shfl_xor(a0, 2); a0 += __shfl_xor(a0, 4);
    a1 += __shfl_xor(a1, 1); a1 += __shfl_xor(a1, 2); a1 += __shfl_xor(a1, 4);
    a2 += __shfl_xor(a2, 1); a2 += __shfl_xor(a2, 2); a2 += __shfl_xor(a2, 4);
    if (hh == 0) {
      float* po = Out + (size_t)MTOT * 256;
      po[(size_t)m * 3 + 0] = a0 + bpo[0];
      po[(size_t)m * 3 + 1] = a1 + bpo[1];
      po[(size_t)m * 3 + 2] = a2 + bpo[2];
    }
    return;
  }

  __shared__ __align__(16) short As[64 * 136];
  __shared__ __align__(16) short Bs[64 * 136];
  int n0 = blockIdx.y * 64;
  int lane = tid & 63, w = tid >> 6;
  int t = lane & 15, g = lane >> 4, kf = g * 8;
  int wm = w & 3, wn = w >> 2;
  f32x4 acc[2] = {};
  int srow = tid >> 3, skc = (tid & 7) * 16;
  for (int ph = 0; ph < 2; ph++) {
    int k0 = ph * 128;
    __syncthreads();
    {
      int kg = k0 + skc;
      int hh = kg >> 5, d0 = kg & 31;
      size_t rowO = (size_t)(b * 8 + hh) * S_ + sbase + srow;
      float inv = 1.0f / (AccL[rowO] + AccL[(size_t)NBH * S_ + rowO]);
#pragma unroll
      for (int half = 0; half < 2; half++) {
        short8 a0 = *reinterpret_cast<const short8*>(&Ctx[rowO * 48 + d0 + half * 8]);
        short8 a1 = *reinterpret_cast<const short8*>(&Ctx[CTXSZ + rowO * 48 + d0 + half * 8]);
        short8 o;
#pragma unroll
        for (int c = 0; c < 8; c++)
          o[c] = bf16_of((f_of_bf16(a0[c]) + f_of_bf16(a1[c])) * inv);
        *reinterpret_cast<short8*>(&As[srow * 136 + skc + half * 8]) = o;
      }
      *reinterpret_cast<uint4*>(&Bs[srow * 136 + skc]) =
          *reinterpret_cast<const uint4*>(&Wot[(size_t)(n0 + srow) * 256 + kg]);
      *reinterpret_cast<uint4*>(&Bs[srow * 136 + skc + 8]) =
          *reinterpret_cast<const uint4*>(&Wot[(size_t)(n0 + srow) * 256 + kg + 8]);
    }
    __syncthreads();
#pragma unroll
    for (int kk = 0; kk < 4; kk++) {
      short8 a = *reinterpret_cast<const short8*>(&As[(wm * 16 + t) * 136 + kk * 32 + kf]);
#pragma unroll
      for (int jj = 0; jj < 2; jj++) {
        short8 bb = *reinterpret_cast<const short8*>(&Bs[(wn * 32 + jj * 16 + t) * 136 + kk * 32 + kf]);
        acc[jj] = __builtin_amdgcn_mfma_f32_16x16x32_bf16(a, bb, acc[jj], 0, 0, 0);
      }
    }
  }
#pragma unroll
  for (int jj = 0; jj < 2; jj++)
#pragma unroll
    for (int r = 0; r < 4; r++) {
      int mrow = m0 + wm * 16 + g * 4 + r;
      int n = n0 + wn * 32 + jj * 16 + t;
      Out[(size_t)mrow * 256 + n] = acc[jj][r] + bo[n];
    }
}

// ---------------- launch ----------------

extern "C" void kernel_launch(void* const* d_in, const int* in_sizes, int n_in,
                              void* d_out, int out_size, void* d_ws, size_t ws_size,
                              hipStream_t stream) {
  const float* seq    = (const float*)d_in[0];
  const float* coords = (const float*)d_in[1];
  const int*   mask   = (const int*)d_in[3];
  const float* Wq  = (const float*)d_in[4];
  const float* bq  = (const float*)d_in[5];
  const float* Wk  = (const float*)d_in[6];
  const float* bk  = (const float*)d_in[7];
  const float* Wv  = (const float*)d_in[8];
  const float* bv  = (const float*)d_in[9];
  const float* Wpq = (const float*)d_in[10];
  const float* bpq = (const float*)d_in[11];
  const float* Wpk = (const float*)d_in[12];
  const float* bpk = (const float*)d_in[13];
  const float* Wo  = (const float*)d_in[14];
  const float* bo  = (const float*)d_in[15];
  const float* Wpo = (const float*)d_in[16];
  const float* bpo = (const float*)d_in[17];
  float* out = (float*)d_out;

  char* ws = (char*)d_ws;
  short* Wqkv_t = (short*)ws; ws += 768 * 256 * 2;
  short* Wo_t   = (short*)ws; ws += 256 * 256 * 2;
  short* Qa     = (short*)ws; ws += (size_t)NBH * S_ * AUGQ * 2;
  short* Ka     = (short*)ws; ws += (size_t)NBH * S_ * AUGQ * 2;
  short* VaT    = (short*)ws; ws += (size_t)NBH * 48 * S_ * 2;
  short* Ctx    = (short*)ws; ws += (size_t)NSPLIT * NBH * S_ * 48 * 2;
  float* AccL   = (float*)ws; ws += (size_t)NSPLIT * NBH * S_ * 4;

  prep_all<<<1024, 256, 0, stream>>>(Wq, Wk, Wv, Wo, coords, mask, Wpq, bpq, Wpk, bpk,
                                     Wqkv_t, Wo_t, Qa, Ka, VaT);
  qkv_gemm<<<dim3(64, 12), 256, 0, stream>>>(seq, Wqkv_t, bq, bk, bv, Qa, Ka, VaT);
  attn<<<512, 256, 0, stream>>>(Qa, Ka, VaT, Ctx, AccL);
  out_gemm<<<dim3(64, 5), 512, 0, stream>>>(Ctx, AccL, Wo_t, bo, Wpo, bpo, out);
}

// Round 8
// 65.757 us; speedup vs baseline: 1.7657x; 1.0572x over previous
//
#include <hip/hip_runtime.h>
#include <hip/hip_bf16.h>

#define D_ 256
#define H_ 8
#define B_ 2
#define S_ 2048
#define MTOT 4096
#define AUGQ 64          // q(32) + pq(16) + [maskbias](1) + pad(15)
#define NBH 16           // B_*H_
#define KPAD 72
#define NSPLIT 4
#define NJ 8             // key tiles (of 64) per split
#define LOG2E 1.4426950408889634f

typedef __attribute__((ext_vector_type(8))) short short8;
typedef __attribute__((ext_vector_type(4))) short short4v;
typedef __attribute__((ext_vector_type(4))) float f32x4;

static __device__ __forceinline__ short bf16_of(float f) {
  union { __hip_bfloat16 h; short s; } u;
  u.h = __float2bfloat16(f);
  return u.s;
}
static __device__ __forceinline__ float f_of_bf16(short s) {
  union { float f; unsigned int u; } u;
  u.u = ((unsigned int)(unsigned short)s) << 16;
  return u.f;
}

// key permutation within a 64-key tile: V column c holds key sinv(c)
// sinv(c): w=(c>>5)&1, g=(c>>3)&3, u=(c>>2)&1, r=c&3 -> ((u<<1|w)<<4)+(g<<2)+r
static __device__ __forceinline__ int sinv64(int c) {
  return (((((c >> 2) & 1) << 1) | ((c >> 5) & 1)) << 4) + (((c >> 3) & 3) << 2) + (c & 3);
}

// ---------------- fused prep: weights cvt/transpose + pq/pk fills ----------------

__global__ void prep_all(const float* __restrict__ Wq, const float* __restrict__ Wk,
                         const float* __restrict__ Wv, const float* __restrict__ Wo,
                         const float* __restrict__ coords, const int* __restrict__ mask,
                         const float* __restrict__ Wpq, const float* __restrict__ bpq,
                         const float* __restrict__ Wpk, const float* __restrict__ bpk,
                         short* __restrict__ Wqkv_t, short* __restrict__ Wo_t,
                         short* __restrict__ Qa, short* __restrict__ Ka,
                         short* __restrict__ VaT) {
  int gid = blockIdx.x * 256 + threadIdx.x;
  int NT = gridDim.x * 256;
  for (int idx = gid; idx < 768 * 256; idx += NT) {
    int n = idx >> 8, k = idx & 255;
    const float* W = (n < 256) ? Wq : (n < 512 ? Wk : Wv);
    Wqkv_t[idx] = bf16_of(W[k * 256 + (n & 255)]);
  }
  for (int idx = gid; idx < 256 * 256; idx += NT) {
    int n = idx >> 8, k = idx & 255;
    Wo_t[idx] = bf16_of(Wo[k * 256 + n]);
  }
  // pq/pk augmented cols (Q side pre-scaled by log2e for exp2 softmax)
  for (int idx = gid; idx < MTOT * 8; idx += NT) {
    int m = idx >> 3, h = idx & 7;
    int b = m >> 11, s = m & 2047;
    float r0 = coords[m * 9 + 3], r1 = coords[m * 9 + 4], r2 = coords[m * 9 + 5];
    size_t base = ((size_t)(b * 8 + h) * S_ + s) * AUGQ;
    short8 pqv[2], pkv[2];
#pragma unroll
    for (int c = 0; c < 2; c++)
#pragma unroll
      for (int i = 0; i < 8; i++) {
        int j = h * 16 + c * 8 + i;
        float pq = r0 * Wpq[j] + r1 * Wpq[128 + j] + r2 * Wpq[256 + j] + bpq[j];
        float pk = r0 * Wpk[j] + r1 * Wpk[128 + j] + r2 * Wpk[256 + j] + bpk[j];
        pqv[c][i] = bf16_of(pq * LOG2E);
        pkv[c][i] = bf16_of(pk * 0.25f);
      }
    short8 padq = {};
    padq[0] = bf16_of(LOG2E);  // multiplies Ka's mask-bias col
    short8 padk = {};
    padk[0] = mask[m] ? (short)0 : bf16_of(-1e9f);
    short8 z = {};
    *reinterpret_cast<short8*>(&Qa[base + 32]) = pqv[0];
    *reinterpret_cast<short8*>(&Qa[base + 40]) = pqv[1];
    *reinterpret_cast<short8*>(&Qa[base + 48]) = padq;
    *reinterpret_cast<short8*>(&Qa[base + 56]) = z;
    *reinterpret_cast<short8*>(&Ka[base + 32]) = pkv[0];
    *reinterpret_cast<short8*>(&Ka[base + 40]) = pkv[1];
    *reinterpret_cast<short8*>(&Ka[base + 48]) = padk;
    *reinterpret_cast<short8*>(&Ka[base + 56]) = z;
  }
  // pq (unscaled) into VaT (transposed layout [bh][32+p][s], keys sigma-permuted per 64)
  for (int idx = gid; idx < NBH * 16 * (S_ / 8); idx += NT) {
    int s8 = idx & 255, p = (idx >> 8) & 15, bh = idx >> 12;
    int b = bh >> 3, h = bh & 7, j = h * 16 + p;
    float w0 = Wpq[j], w1 = Wpq[128 + j], w2 = Wpq[256 + j], bb = bpq[j];
    short8 o;
#pragma unroll
    for (int i = 0; i < 8; i++) {
      int c = (s8 & 7) * 8 + i;
      int m = b * 2048 + (s8 >> 3) * 64 + sinv64(c);
      o[i] = bf16_of(coords[m * 9 + 3] * w0 + coords[m * 9 + 4] * w1 +
                     coords[m * 9 + 5] * w2 + bb);
    }
    *reinterpret_cast<short8*>(&VaT[((size_t)bh * 48 + 32 + p) * S_ + s8 * 8]) = o;
  }
}

// ---------------- QKV GEMM (M=4096, N=768, K=256), f32 input, vector epilogue ----------------

__global__ __launch_bounds__(256) void qkv_gemm(
    const float* __restrict__ X, const short* __restrict__ Wt,
    const float* __restrict__ bq, const float* __restrict__ bk, const float* __restrict__ bv,
    short* __restrict__ Qa, short* __restrict__ Ka, short* __restrict__ VaT) {
  __shared__ __align__(16) short As[64 * 136];
  __shared__ __align__(16) short Bs[64 * 136];
  int m0 = blockIdx.x * 64, n0 = blockIdx.y * 64;
  int tid = threadIdx.x, lane = tid & 63, w = tid >> 6;
  int t = lane & 15, g = lane >> 4, kf = g * 8;
  int wr = (w >> 1) * 32, wc = (w & 1) * 32;
  f32x4 acc[2][2] = {};
  int srow = tid >> 2, skc = (tid & 3) * 32;
  for (int ph = 0; ph < 2; ph++) {
    int k0 = ph * 128;
    __syncthreads();
    {
      const float* xs = &X[(size_t)(m0 + srow) * 256 + k0 + skc];
      short4v av[8];
#pragma unroll
      for (int i = 0; i < 8; i++) {
        f32x4 xv = *reinterpret_cast<const f32x4*>(&xs[i * 4]);
        short4v o;
        o[0] = bf16_of(xv[0]); o[1] = bf16_of(xv[1]);
        o[2] = bf16_of(xv[2]); o[3] = bf16_of(xv[3]);
        av[i] = o;
      }
#pragma unroll
      for (int i = 0; i < 8; i++)
        *reinterpret_cast<short4v*>(&As[srow * 136 + skc + i * 4]) = av[i];
      const uint4* wsrc = reinterpret_cast<const uint4*>(&Wt[(size_t)(n0 + srow) * 256 + k0 + skc]);
#pragma unroll
      for (int i = 0; i < 4; i++)
        *reinterpret_cast<uint4*>(&Bs[srow * 136 + skc + i * 8]) = wsrc[i];
    }
    __syncthreads();
#pragma unroll
    for (int kk = 0; kk < 4; kk++) {
      short8 a[2], bb[2];
#pragma unroll
      for (int i = 0; i < 2; i++)
        a[i] = *reinterpret_cast<const short8*>(&As[(wr + i * 16 + t) * 136 + kk * 32 + kf]);
#pragma unroll
      for (int jj = 0; jj < 2; jj++)
        bb[jj] = *reinterpret_cast<const short8*>(&Bs[(wc + jj * 16 + t) * 136 + kk * 32 + kf]);
#pragma unroll
      for (int i = 0; i < 2; i++)
#pragma unroll
        for (int jj = 0; jj < 2; jj++)
          acc[i][jj] = __builtin_amdgcn_mfma_f32_16x16x32_bf16(a[i], bb[jj], acc[i][jj], 0, 0, 0);
    }
  }
  // epilogue: bias/scale -> LDS bf16 tile -> vector stores
  __syncthreads();
  short* Cs = As;
  const float scale = 0.17677669529663687f * LOG2E;  // (1/sqrt(32)) * log2e
  int b = m0 >> 11, sbase = m0 & 2047;
#pragma unroll
  for (int i = 0; i < 2; i++)
#pragma unroll
    for (int jj = 0; jj < 2; jj++)
#pragma unroll
      for (int r = 0; r < 4; r++) {
        int rl = wr + i * 16 + g * 4 + r;
        int cl = wc + jj * 16 + t;
        int n = n0 + cl;
        float v = acc[i][jj][r];
        if (n < 256) v = (v + bq[n]) * scale;
        else if (n < 512) v = v + bk[n - 256];
        else v = v + bv[n - 512];
        Cs[rl * 72 + cl] = bf16_of(v);
      }
  __syncthreads();
  if (n0 < 512) {
#pragma unroll
    for (int i2 = 0; i2 < 2; i2++) {
      int task = tid + i2 * 256;
      int row = task >> 3, c = task & 7;
      int n = n0 + c * 8;
      short* dst = (n < 256) ? Qa : Ka;
      int nn = n & 255;
      int hh = nn >> 5, d = nn & 31;
      *reinterpret_cast<short8*>(&dst[((size_t)(b * 8 + hh) * S_ + sbase + row) * AUGQ + d]) =
          *reinterpret_cast<const short8*>(&Cs[row * 72 + c * 8]);
    }
  } else {
    int hv0 = (n0 - 512) >> 5;
#pragma unroll
    for (int i2 = 0; i2 < 2; i2++) {
      int task = tid + i2 * 256;
      int fl = task >> 3, s8 = task & 7;
      short8 o;
#pragma unroll
      for (int i = 0; i < 8; i++) o[i] = Cs[sinv64(s8 * 8 + i) * 72 + fl];
      int hh = hv0 + (fl >> 5), d = fl & 31;
      *reinterpret_cast<short8*>(&VaT[((size_t)(b * 8 + hh) * 48 + d) * S_ + sbase + s8 * 8]) = o;
    }
  }
}

// ---------------- flash attention: swapped QK^T, register P, K=32 PV ----------------
// grid 1024 (XCD-swizzled, 4 blocks/CU); block 256 = 4 waves, each wave 32 queries.
// Double-buffered LDS: Kb0 @0 (9216B), Kb1 @9216, Vb0 @18432 (6912B), Vb1 @25344.
// V keys are sigma-permuted so QK outputs form K=32 PV fragments in-register.

__global__ __launch_bounds__(256, 4) void attn(
    const short* __restrict__ Qa, const short* __restrict__ Ka,
    const short* __restrict__ VaT,
    short* __restrict__ Ctx, float* __restrict__ AccL) {
  __shared__ __align__(16) char smem[32256];

  // XCD decode: xcd = bid&7 owns 2 bh streams (~900KB KV, L2-resident)
  int bid = blockIdx.x;
  int xcd = bid & 7, slot = bid >> 3;       // slot 0..127
  int gidx = xcd * 8 + (slot >> 4);         // 0..63 = bhv*4+split
  int it = slot & 15;
  int split = gidx & 3;
  int bhv = gidx >> 2;

  int tid = threadIdx.x, lane = tid & 63, w = tid >> 6;
  int t = lane & 15, g = lane >> 4, kf = g * 8;
  int q0w = it * 128 + w * 32;
  size_t bh = (size_t)bhv * S_;

  short8 aq[2][2];
#pragma unroll
  for (int g2 = 0; g2 < 2; g2++)
#pragma unroll
    for (int c = 0; c < 2; c++)
      aq[g2][c] = *reinterpret_cast<const short8*>(
          &Qa[(bh + q0w + g2 * 16 + t) * AUGQ + c * 32 + kf]);

  f32x4 OaccA[3] = {}, OaccB[3] = {};
  float lsum0 = 0.f, lsum1 = 0.f;

  uint4 kreg0, kreg1, vreg0, vreg1;
  int srow = tid >> 3, sko = (tid & 7) * 8;
  const int jt0 = split * NJ;

  auto issue = [&](int jt) {
    const uint4* ks = reinterpret_cast<const uint4*>(&Ka[(bh + jt * 64) * AUGQ]);
    kreg0 = ks[tid];
    kreg1 = ks[tid + 256];
    size_t vb = (size_t)bhv * 48 * S_ + jt * 64;
    vreg0 = *reinterpret_cast<const uint4*>(&VaT[vb + (size_t)srow * S_ + sko]);
    if (tid < 128)
      vreg1 = *reinterpret_cast<const uint4*>(&VaT[vb + (size_t)(srow + 32) * S_ + sko]);
  };
  auto commit = [&](int buf) {
    short* Kd = (short*)(smem + buf * 9216);
    short* Vd = (short*)(smem + 18432 + buf * 6912);
    *reinterpret_cast<uint4*>(&Kd[srow * KPAD + sko]) = kreg0;
    *reinterpret_cast<uint4*>(&Kd[(srow + 32) * KPAD + sko]) = kreg1;
    *reinterpret_cast<uint4*>(&Vd[srow * KPAD + sko]) = vreg0;
    if (tid < 128)
      *reinterpret_cast<uint4*>(&Vd[(srow + 32) * KPAD + sko]) = vreg1;
  };

  issue(jt0);
  commit(0);
  __syncthreads();

  for (int j = 0; j < NJ; j++) {
    int cur = j & 1;
    if (j + 1 < NJ) issue(jt0 + j + 1);
    const short* Kc = (const short*)(smem + cur * 9216);
    const short* Vc = (const short*)(smem + 18432 + cur * 6912);
    short8 pA[2], pB[2];
#pragma unroll
    for (int sub = 0; sub < 4; sub++) {
      short8 ka0 = *reinterpret_cast<const short8*>(&Kc[(sub * 16 + t) * KPAD + kf]);
      short8 ka1 = *reinterpret_cast<const short8*>(&Kc[(sub * 16 + t) * KPAD + 32 + kf]);
      f32x4 sA = {}, sB = {};
      sA = __builtin_amdgcn_mfma_f32_16x16x32_bf16(ka0, aq[0][0], sA, 0, 0, 0);
      sA = __builtin_amdgcn_mfma_f32_16x16x32_bf16(ka1, aq[0][1], sA, 0, 0, 0);
      sB = __builtin_amdgcn_mfma_f32_16x16x32_bf16(ka0, aq[1][0], sB, 0, 0, 0);
      sB = __builtin_amdgcn_mfma_f32_16x16x32_bf16(ka1, aq[1][1], sB, 0, 0, 0);
      float a0 = exp2f(sA[0]), a1 = exp2f(sA[1]), a2 = exp2f(sA[2]), a3 = exp2f(sA[3]);
      float b0 = exp2f(sB[0]), b1 = exp2f(sB[1]), b2 = exp2f(sB[2]), b3 = exp2f(sB[3]);
      lsum0 += (a0 + a1) + (a2 + a3);
      lsum1 += (b0 + b1) + (b2 + b3);
      int ww = sub & 1, off = (sub >> 1) * 4;
      pA[ww][off + 0] = bf16_of(a0); pA[ww][off + 1] = bf16_of(a1);
      pA[ww][off + 2] = bf16_of(a2); pA[ww][off + 3] = bf16_of(a3);
      pB[ww][off + 0] = bf16_of(b0); pB[ww][off + 1] = bf16_of(b1);
      pB[ww][off + 2] = bf16_of(b2); pB[ww][off + 3] = bf16_of(b3);
    }
    __builtin_amdgcn_s_setprio(1);
#pragma unroll
    for (int tt = 0; tt < 3; tt++) {
#pragma unroll
      for (int w2 = 0; w2 < 2; w2++) {
        short8 va = *reinterpret_cast<const short8*>(&Vc[(tt * 16 + t) * KPAD + w2 * 32 + kf]);
        OaccA[tt] = __builtin_amdgcn_mfma_f32_16x16x32_bf16(va, pA[w2], OaccA[tt], 0, 0, 0);
        OaccB[tt] = __builtin_amdgcn_mfma_f32_16x16x32_bf16(va, pB[w2], OaccB[tt], 0, 0, 0);
      }
    }
    __builtin_amdgcn_s_setprio(0);
    if (j + 1 < NJ) commit(cur ^ 1);
    __syncthreads();
  }

  // epilogue: reduce lsums; transpose O via LDS overlay; bf16 partial ctx out
  lsum0 += __shfl_xor(lsum0, 16); lsum0 += __shfl_xor(lsum0, 32);
  lsum1 += __shfl_xor(lsum1, 16); lsum1 += __shfl_xor(lsum1, 32);

  float* Of = (float*)smem;  // 128 x 52 f32 overlay
#pragma unroll
  for (int tt = 0; tt < 3; tt++)
#pragma unroll
    for (int r = 0; r < 4; r++) {
      Of[(w * 32 + t) * 52 + tt * 16 + g * 4 + r] = OaccA[tt][r];
      Of[(w * 32 + 16 + t) * 52 + tt * 16 + g * 4 + r] = OaccB[tt][r];
    }
  if (lane < 16) {
    size_t lb = (size_t)(split * NBH + bhv) * S_ + q0w + lane;
    AccL[lb] = lsum0;
    AccL[lb + 16] = lsum1;
  }
  __syncthreads();
  short* CtxP = Ctx + (size_t)split * NBH * S_ * 48;
  size_t obase = bh + it * 128;
  for (int task = tid; task < 768; task += 256) {
    int row = task / 6, c8 = task % 6;
    const float* src = &Of[row * 52 + c8 * 8];
    short8 o;
#pragma unroll
    for (int i = 0; i < 8; i++) o[i] = bf16_of(src[i]);
    *reinterpret_cast<short8*>(&CtxP[(obase + row) * 48 + c8 * 8]) = o;
  }
}

// ---------------- output projection + fused 4-way split-merge + fused point_proj ----------------
// grid (64, 5), 512 threads. y<4: seq_out GEMM n-slice. y==4: point_out.

__global__ __launch_bounds__(512) void out_gemm(
    const short* __restrict__ Ctx, const float* __restrict__ AccL,
    const short* __restrict__ Wot, const float* __restrict__ bo,
    const float* __restrict__ Wpo, const float* __restrict__ bpo,
    float* __restrict__ Out) {
  const size_t CTXSZ = (size_t)NBH * S_ * 48;
  int m0 = blockIdx.x * 64;
  int tid = threadIdx.x;
  int b = m0 >> 11, sbase = m0 & 2047;

  if (blockIdx.y == 4) {
    // point_out: 8 threads per row, one head each
    int row = tid >> 3, hh = tid & 7;
    int m = m0 + row, s = sbase + row;
    size_t rowO = (size_t)(b * 8 + hh) * S_ + s;
    float l = 0.f;
#pragma unroll
    for (int sp = 0; sp < NSPLIT; sp++) l += AccL[(size_t)sp * NBH * S_ + rowO];
    float inv = 1.0f / l;
    float a0 = 0.f, a1 = 0.f, a2 = 0.f;
#pragma unroll
    for (int half = 0; half < 2; half++) {
      float sum[8] = {};
#pragma unroll
      for (int sp = 0; sp < NSPLIT; sp++) {
        short8 v = *reinterpret_cast<const short8*>(&Ctx[sp * CTXSZ + rowO * 48 + 32 + half * 8]);
#pragma unroll
        for (int c = 0; c < 8; c++) sum[c] += f_of_bf16(v[c]);
      }
#pragma unroll
      for (int c = 0; c < 8; c++) {
        float val = sum[c] * inv;
        int j = hh * 16 + half * 8 + c;
        a0 += val * Wpo[j * 3 + 0];
        a1 += val * Wpo[j * 3 + 1];
        a2 += val * Wpo[j * 3 + 2];
      }
    }
    a0 += __shfl_xor(a0, 1); a0 += __shfl_xor(a0, 2); a0 += __shfl_xor(a0, 4);
    a1 += __shfl_xor(a1, 1); a1 += __shfl_xor(a1, 2); a1 += __shfl_xor(a1, 4);
    a2 += __shfl_xor(a2, 1); a2 += __shfl_xor(a2, 2); a2 += __shfl_xor(a2, 4);
    if (hh == 0) {
      float* po = Out + (size_t)MTOT * 256;
      po[(size_t)m * 3 + 0] = a0 + bpo[0];
      po[(size_t)m * 3 + 1] = a1 + bpo[1];
      po[(size_t)m * 3 + 2] = a2 + bpo[2];
    }
    return;
  }

  __shared__ __align__(16) short As[64 * 136];
  __shared__ __align__(16) short Bs[64 * 136];
  int n0 = blockIdx.y * 64;
  int lane = tid & 63, w = tid >> 6;
  int t = lane & 15, g = lane >> 4, kf = g * 8;
  int wm = w & 3, wn = w >> 2;
  f32x4 acc[2] = {};
  int srow = tid >> 3, skc = (tid & 7) * 16;
  for (int ph = 0; ph < 2; ph++) {
    int k0 = ph * 128;
    __syncthreads();
    {
      int kg = k0 + skc;
      int hh = kg >> 5, d0 = kg & 31;
      size_t rowO = (size_t)(b * 8 + hh) * S_ + sbase + srow;
      float l = 0.f;
#pragma unroll
      for (int sp = 0; sp < NSPLIT; sp++) l += AccL[(size_t)sp * NBH * S_ + rowO];
      float inv = 1.0f / l;
#pragma unroll
      for (int half = 0; half < 2; half++) {
        float sum[8] = {};
#pragma unroll
        for (int sp = 0; sp < NSPLIT; sp++) {
          short8 a = *reinterpret_cast<const short8*>(&Ctx[sp * CTXSZ + rowO * 48 + d0 + half * 8]);
#pragma unroll
          for (int c = 0; c < 8; c++) sum[c] += f_of_bf16(a[c]);
        }
        short8 o;
#pragma unroll
        for (int c = 0; c < 8; c++) o[c] = bf16_of(sum[c] * inv);
        *reinterpret_cast<short8*>(&As[srow * 136 + skc + half * 8]) = o;
      }
      *reinterpret_cast<uint4*>(&Bs[srow * 136 + skc]) =
          *reinterpret_cast<const uint4*>(&Wot[(size_t)(n0 + srow) * 256 + kg]);
      *reinterpret_cast<uint4*>(&Bs[srow * 136 + skc + 8]) =
          *reinterpret_cast<const uint4*>(&Wot[(size_t)(n0 + srow) * 256 + kg + 8]);
    }
    __syncthreads();
#pragma unroll
    for (int kk = 0; kk < 4; kk++) {
      short8 a = *reinterpret_cast<const short8*>(&As[(wm * 16 + t) * 136 + kk * 32 + kf]);
#pragma unroll
      for (int jj = 0; jj < 2; jj++) {
        short8 bb = *reinterpret_cast<const short8*>(&Bs[(wn * 32 + jj * 16 + t) * 136 + kk * 32 + kf]);
        acc[jj] = __builtin_amdgcn_mfma_f32_16x16x32_bf16(a, bb, acc[jj], 0, 0, 0);
      }
    }
  }
#pragma unroll
  for (int jj = 0; jj < 2; jj++)
#pragma unroll
    for (int r = 0; r < 4; r++) {
      int mrow = m0 + wm * 16 + g * 4 + r;
      int n = n0 + wn * 32 + jj * 16 + t;
      Out[(size_t)mrow * 256 + n] = acc[jj][r] + bo[n];
    }
}

// ---------------- launch ----------------

extern "C" void kernel_launch(void* const* d_in, const int* in_sizes, int n_in,
                              void* d_out, int out_size, void* d_ws, size_t ws_size,
                              hipStream_t stream) {
  const float* seq    = (const float*)d_in[0];
  const float* coords = (const float*)d_in[1];
  const int*   mask   = (const int*)d_in[3];
  const float* Wq  = (const float*)d_in[4];
  const float* bq  = (const float*)d_in[5];
  const float* Wk  = (const float*)d_in[6];
  const float* bk  = (const float*)d_in[7];
  const float* Wv  = (const float*)d_in[8];
  const float* bv  = (const float*)d_in[9];
  const float* Wpq = (const float*)d_in[10];
  const float* bpq = (const float*)d_in[11];
  const float* Wpk = (const float*)d_in[12];
  const float* bpk = (const float*)d_in[13];
  const float* Wo  = (const float*)d_in[14];
  const float* bo  = (const float*)d_in[15];
  const float* Wpo = (const float*)d_in[16];
  const float* bpo = (const float*)d_in[17];
  float* out = (float*)d_out;

  char* ws = (char*)d_ws;
  short* Wqkv_t = (short*)ws; ws += 768 * 256 * 2;
  short* Wo_t   = (short*)ws; ws += 256 * 256 * 2;
  short* Qa     = (short*)ws; ws += (size_t)NBH * S_ * AUGQ * 2;
  short* Ka     = (short*)ws; ws += (size_t)NBH * S_ * AUGQ * 2;
  short* VaT    = (short*)ws; ws += (size_t)NBH * 48 * S_ * 2;
  short* Ctx    = (short*)ws; ws += (size_t)NSPLIT * NBH * S_ * 48 * 2;
  float* AccL   = (float*)ws; ws += (size_t)NSPLIT * NBH * S_ * 4;

  prep_all<<<1024, 256, 0, stream>>>(Wq, Wk, Wv, Wo, coords, mask, Wpq, bpq, Wpk, bpk,
                                     Wqkv_t, Wo_t, Qa, Ka, VaT);
  qkv_gemm<<<dim3(64, 12), 256, 0, stream>>>(seq, Wqkv_t, bq, bk, bv, Qa, Ka, VaT);
  attn<<<1024, 256, 0, stream>>>(Qa, Ka, VaT, Ctx, AccL);
  out_gemm<<<dim3(64, 5), 512, 0, stream>>>(Ctx, AccL, Wo_t, bo, Wpo, bpo, out);
}

// Round 9
// 60.205 us; speedup vs baseline: 1.9286x; 1.0922x over previous
//
#include <hip/hip_runtime.h>
#include <hip/hip_bf16.h>

#define D_ 256
#define H_ 8
#define B_ 2
#define S_ 2048
#define MTOT 4096
#define AUGQ 64          // q(32) + pq(16) + [maskbias](1) + pad(15)
#define NBH 16           // B_*H_
#define KPAD 72
#define NSPLIT 4
#define NJ 8             // key tiles (of 64) per split
#define LOG2E 1.4426950408889634f

typedef __attribute__((ext_vector_type(8))) short short8;
typedef __attribute__((ext_vector_type(4))) short short4v;
typedef __attribute__((ext_vector_type(4))) float f32x4;

static __device__ __forceinline__ short bf16_of(float f) {
  union { __hip_bfloat16 h; short s; } u;
  u.h = __float2bfloat16(f);
  return u.s;
}
static __device__ __forceinline__ float f_of_bf16(short s) {
  union { float f; unsigned int u; } u;
  u.u = ((unsigned int)(unsigned short)s) << 16;
  return u.f;
}

// key permutation within a 64-key tile: V column c holds key sinv(c)
static __device__ __forceinline__ int sinv64(int c) {
  return (((((c >> 2) & 1) << 1) | ((c >> 5) & 1)) << 4) + (((c >> 3) & 3) << 2) + (c & 3);
}

// ---------------- prep: sectioned by blockIdx ----------------
// blocks 0..47   : Wqkv transpose tiles (64x64 via LDS)
// blocks 48..63  : Wo transpose tiles
// blocks 64..575 : X f32 -> bf16 (Xb)
// blocks 576..703: pq/pk augmented cols
// blocks 704..959: pq into VaT (sigma-permuted)

__global__ __launch_bounds__(256) void prep_all(
    const float* __restrict__ Wq, const float* __restrict__ Wk,
    const float* __restrict__ Wv, const float* __restrict__ Wo,
    const float* __restrict__ X, const float* __restrict__ coords,
    const int* __restrict__ mask,
    const float* __restrict__ Wpq, const float* __restrict__ bpq,
    const float* __restrict__ Wpk, const float* __restrict__ bpk,
    short* __restrict__ Wqkv_t, short* __restrict__ Wo_t,
    short* __restrict__ Xb,
    short* __restrict__ Qa, short* __restrict__ Ka, short* __restrict__ VaT) {
  int bid = blockIdx.x, tid = threadIdx.x;

  if (bid < 64) {
    // --- weight transpose tile ---
    __shared__ short T[64][72];
    const float* src;
    short* dst;
    int k0, n0g;
    if (bid < 48) {
      int nt = bid >> 2;           // 0..11 -> n0g = nt*64 in 0..704
      k0 = (bid & 3) * 64;
      n0g = nt * 64;
      src = (n0g < 256) ? Wq : (n0g < 512 ? Wk : Wv);
      dst = Wqkv_t;
    } else {
      int t2 = bid - 48;
      k0 = (t2 & 3) * 64;
      n0g = (t2 >> 2) * 64;
      src = Wo;
      dst = Wo_t;
    }
    int ncol = n0g & 255;
    int rr = tid >> 4, cc = (tid & 15) * 4;
#pragma unroll
    for (int i = 0; i < 4; i++) {
      int r = rr + i * 16;
      f32x4 v = *reinterpret_cast<const f32x4*>(&src[(size_t)(k0 + r) * 256 + ncol + cc]);
      T[cc + 0][r] = bf16_of(v[0]);
      T[cc + 1][r] = bf16_of(v[1]);
      T[cc + 2][r] = bf16_of(v[2]);
      T[cc + 3][r] = bf16_of(v[3]);
    }
    __syncthreads();
    int n = tid >> 2, kk = (tid & 3) * 16;
    *reinterpret_cast<short8*>(&dst[(size_t)(n0g + n) * 256 + k0 + kk]) =
        *reinterpret_cast<const short8*>(&T[n][kk]);
    *reinterpret_cast<short8*>(&dst[(size_t)(n0g + n) * 256 + k0 + kk + 8]) =
        *reinterpret_cast<const short8*>(&T[n][kk + 8]);
    return;
  }

  if (bid < 576) {
    // --- X -> bf16 ---
    size_t i = (size_t)(bid - 64) * 2048 + tid * 8;
    f32x4 v0 = *reinterpret_cast<const f32x4*>(&X[i]);
    f32x4 v1 = *reinterpret_cast<const f32x4*>(&X[i + 4]);
    short8 o;
    o[0] = bf16_of(v0[0]); o[1] = bf16_of(v0[1]); o[2] = bf16_of(v0[2]); o[3] = bf16_of(v0[3]);
    o[4] = bf16_of(v1[0]); o[5] = bf16_of(v1[1]); o[6] = bf16_of(v1[2]); o[7] = bf16_of(v1[3]);
    *reinterpret_cast<short8*>(&Xb[i]) = o;
    return;
  }

  if (bid < 704) {
    // --- pq/pk augmented cols (Q side pre-scaled by log2e) ---
    int idx = (bid - 576) * 256 + tid;   // 0..32767
    int m = idx >> 3, h = idx & 7;
    int b = m >> 11, s = m & 2047;
    float r0 = coords[m * 9 + 3], r1 = coords[m * 9 + 4], r2 = coords[m * 9 + 5];
    size_t base = ((size_t)(b * 8 + h) * S_ + s) * AUGQ;
    short8 pqv[2], pkv[2];
#pragma unroll
    for (int c = 0; c < 2; c++)
#pragma unroll
      for (int i = 0; i < 8; i++) {
        int j = h * 16 + c * 8 + i;
        float pq = r0 * Wpq[j] + r1 * Wpq[128 + j] + r2 * Wpq[256 + j] + bpq[j];
        float pk = r0 * Wpk[j] + r1 * Wpk[128 + j] + r2 * Wpk[256 + j] + bpk[j];
        pqv[c][i] = bf16_of(pq * LOG2E);
        pkv[c][i] = bf16_of(pk * 0.25f);
      }
    short8 padq = {};
    padq[0] = bf16_of(LOG2E);
    short8 padk = {};
    padk[0] = mask[m] ? (short)0 : bf16_of(-1e9f);
    short8 z = {};
    *reinterpret_cast<short8*>(&Qa[base + 32]) = pqv[0];
    *reinterpret_cast<short8*>(&Qa[base + 40]) = pqv[1];
    *reinterpret_cast<short8*>(&Qa[base + 48]) = padq;
    *reinterpret_cast<short8*>(&Qa[base + 56]) = z;
    *reinterpret_cast<short8*>(&Ka[base + 32]) = pkv[0];
    *reinterpret_cast<short8*>(&Ka[base + 40]) = pkv[1];
    *reinterpret_cast<short8*>(&Ka[base + 48]) = padk;
    *reinterpret_cast<short8*>(&Ka[base + 56]) = z;
    return;
  }

  {
    // --- pq (unscaled) into VaT, sigma-permuted per 64 ---
    int idx = (bid - 704) * 256 + tid;   // 0..65535
    int s8 = idx & 255, p = (idx >> 8) & 15, bh = idx >> 12;
    int b = bh >> 3, h = bh & 7, j = h * 16 + p;
    float w0 = Wpq[j], w1 = Wpq[128 + j], w2 = Wpq[256 + j], bb = bpq[j];
    short8 o;
#pragma unroll
    for (int i = 0; i < 8; i++) {
      int c = (s8 & 7) * 8 + i;
      int m = b * 2048 + (s8 >> 3) * 64 + sinv64(c);
      o[i] = bf16_of(coords[m * 9 + 3] * w0 + coords[m * 9 + 4] * w1 +
                     coords[m * 9 + 5] * w2 + bb);
    }
    *reinterpret_cast<short8*>(&VaT[((size_t)bh * 48 + 32 + p) * S_ + s8 * 8]) = o;
  }
}

// ---------------- QKV GEMM (M=4096, N=768, K=256), bf16 in, vector epilogue ----------------

__global__ __launch_bounds__(256) void qkv_gemm(
    const short* __restrict__ Xb, const short* __restrict__ Wt,
    const float* __restrict__ bq, const float* __restrict__ bk, const float* __restrict__ bv,
    short* __restrict__ Qa, short* __restrict__ Ka, short* __restrict__ VaT) {
  __shared__ __align__(16) short As[64 * 136];
  __shared__ __align__(16) short Bs[64 * 136];
  int m0 = blockIdx.x * 64, n0 = blockIdx.y * 64;
  int tid = threadIdx.x, lane = tid & 63, w = tid >> 6;
  int t = lane & 15, g = lane >> 4, kf = g * 8;
  int wr = (w >> 1) * 32, wc = (w & 1) * 32;
  f32x4 acc[2][2] = {};
  int srow = tid >> 2, skc = (tid & 3) * 32;
  for (int ph = 0; ph < 2; ph++) {
    int k0 = ph * 128;
    __syncthreads();
    {
      const uint4* xsrc = reinterpret_cast<const uint4*>(&Xb[(size_t)(m0 + srow) * 256 + k0 + skc]);
      const uint4* wsrc = reinterpret_cast<const uint4*>(&Wt[(size_t)(n0 + srow) * 256 + k0 + skc]);
#pragma unroll
      for (int i = 0; i < 4; i++)
        *reinterpret_cast<uint4*>(&As[srow * 136 + skc + i * 8]) = xsrc[i];
#pragma unroll
      for (int i = 0; i < 4; i++)
        *reinterpret_cast<uint4*>(&Bs[srow * 136 + skc + i * 8]) = wsrc[i];
    }
    __syncthreads();
#pragma unroll
    for (int kk = 0; kk < 4; kk++) {
      short8 a[2], bb[2];
#pragma unroll
      for (int i = 0; i < 2; i++)
        a[i] = *reinterpret_cast<const short8*>(&As[(wr + i * 16 + t) * 136 + kk * 32 + kf]);
#pragma unroll
      for (int jj = 0; jj < 2; jj++)
        bb[jj] = *reinterpret_cast<const short8*>(&Bs[(wc + jj * 16 + t) * 136 + kk * 32 + kf]);
#pragma unroll
      for (int i = 0; i < 2; i++)
#pragma unroll
        for (int jj = 0; jj < 2; jj++)
          acc[i][jj] = __builtin_amdgcn_mfma_f32_16x16x32_bf16(a[i], bb[jj], acc[i][jj], 0, 0, 0);
    }
  }
  // epilogue: bias/scale -> LDS bf16 tile -> vector stores
  __syncthreads();
  short* Cs = As;
  const float scale = 0.17677669529663687f * LOG2E;  // (1/sqrt(32)) * log2e
  int b = m0 >> 11, sbase = m0 & 2047;
#pragma unroll
  for (int i = 0; i < 2; i++)
#pragma unroll
    for (int jj = 0; jj < 2; jj++)
#pragma unroll
      for (int r = 0; r < 4; r++) {
        int rl = wr + i * 16 + g * 4 + r;
        int cl = wc + jj * 16 + t;
        int n = n0 + cl;
        float v = acc[i][jj][r];
        if (n < 256) v = (v + bq[n]) * scale;
        else if (n < 512) v = v + bk[n - 256];
        else v = v + bv[n - 512];
        Cs[rl * 72 + cl] = bf16_of(v);
      }
  __syncthreads();
  if (n0 < 512) {
#pragma unroll
    for (int i2 = 0; i2 < 2; i2++) {
      int task = tid + i2 * 256;
      int row = task >> 3, c = task & 7;
      int n = n0 + c * 8;
      short* dst = (n < 256) ? Qa : Ka;
      int nn = n & 255;
      int hh = nn >> 5, d = nn & 31;
      *reinterpret_cast<short8*>(&dst[((size_t)(b * 8 + hh) * S_ + sbase + row) * AUGQ + d]) =
          *reinterpret_cast<const short8*>(&Cs[row * 72 + c * 8]);
    }
  } else {
    int hv0 = (n0 - 512) >> 5;
#pragma unroll
    for (int i2 = 0; i2 < 2; i2++) {
      int task = tid + i2 * 256;
      int fl = task >> 3, s8 = task & 7;
      short8 o;
#pragma unroll
      for (int i = 0; i < 8; i++) o[i] = Cs[sinv64(s8 * 8 + i) * 72 + fl];
      int hh = hv0 + (fl >> 5), d = fl & 31;
      *reinterpret_cast<short8*>(&VaT[((size_t)(b * 8 + hh) * 48 + d) * S_ + sbase + s8 * 8]) = o;
    }
  }
}

// ---------------- flash attention: swapped QK^T, register P, K=32 PV ----------------
// grid 1024 (XCD-swizzled, 4 blocks/CU); block 256 = 4 waves, each wave 32 queries.
// Double-buffered LDS; V keys sigma-permuted so QK outputs form K=32 PV fragments.

__global__ __launch_bounds__(256, 4) void attn(
    const short* __restrict__ Qa, const short* __restrict__ Ka,
    const short* __restrict__ VaT,
    short* __restrict__ Ctx, float* __restrict__ AccL) {
  __shared__ __align__(16) char smem[32256];

  int bid = blockIdx.x;
  int xcd = bid & 7, slot = bid >> 3;       // slot 0..127
  int gidx = xcd * 8 + (slot >> 4);         // 0..63 = bhv*4+split
  int it = slot & 15;
  int split = gidx & 3;
  int bhv = gidx >> 2;

  int tid = threadIdx.x, lane = tid & 63, w = tid >> 6;
  int t = lane & 15, g = lane >> 4, kf = g * 8;
  int q0w = it * 128 + w * 32;
  size_t bh = (size_t)bhv * S_;

  short8 aq[2][2];
#pragma unroll
  for (int g2 = 0; g2 < 2; g2++)
#pragma unroll
    for (int c = 0; c < 2; c++)
      aq[g2][c] = *reinterpret_cast<const short8*>(
          &Qa[(bh + q0w + g2 * 16 + t) * AUGQ + c * 32 + kf]);

  f32x4 OaccA[3] = {}, OaccB[3] = {};
  float lsum0 = 0.f, lsum1 = 0.f;

  uint4 kreg0, kreg1, vreg0, vreg1;
  int srow = tid >> 3, sko = (tid & 7) * 8;
  const int jt0 = split * NJ;

  auto issue = [&](int jt) {
    const uint4* ks = reinterpret_cast<const uint4*>(&Ka[(bh + jt * 64) * AUGQ]);
    kreg0 = ks[tid];
    kreg1 = ks[tid + 256];
    size_t vb = (size_t)bhv * 48 * S_ + jt * 64;
    vreg0 = *reinterpret_cast<const uint4*>(&VaT[vb + (size_t)srow * S_ + sko]);
    if (tid < 128)
      vreg1 = *reinterpret_cast<const uint4*>(&VaT[vb + (size_t)(srow + 32) * S_ + sko]);
  };
  auto commit = [&](int buf) {
    short* Kd = (short*)(smem + buf * 9216);
    short* Vd = (short*)(smem + 18432 + buf * 6912);
    *reinterpret_cast<uint4*>(&Kd[srow * KPAD + sko]) = kreg0;
    *reinterpret_cast<uint4*>(&Kd[(srow + 32) * KPAD + sko]) = kreg1;
    *reinterpret_cast<uint4*>(&Vd[srow * KPAD + sko]) = vreg0;
    if (tid < 128)
      *reinterpret_cast<uint4*>(&Vd[(srow + 32) * KPAD + sko]) = vreg1;
  };

  issue(jt0);
  commit(0);
  __syncthreads();

  for (int j = 0; j < NJ; j++) {
    int cur = j & 1;
    if (j + 1 < NJ) issue(jt0 + j + 1);
    const short* Kc = (const short*)(smem + cur * 9216);
    const short* Vc = (const short*)(smem + 18432 + cur * 6912);
    short8 pA[2], pB[2];
#pragma unroll
    for (int sub = 0; sub < 4; sub++) {
      short8 ka0 = *reinterpret_cast<const short8*>(&Kc[(sub * 16 + t) * KPAD + kf]);
      short8 ka1 = *reinterpret_cast<const short8*>(&Kc[(sub * 16 + t) * KPAD + 32 + kf]);
      f32x4 sA = {}, sB = {};
      sA = __builtin_amdgcn_mfma_f32_16x16x32_bf16(ka0, aq[0][0], sA, 0, 0, 0);
      sA = __builtin_amdgcn_mfma_f32_16x16x32_bf16(ka1, aq[0][1], sA, 0, 0, 0);
      sB = __builtin_amdgcn_mfma_f32_16x16x32_bf16(ka0, aq[1][0], sB, 0, 0, 0);
      sB = __builtin_amdgcn_mfma_f32_16x16x32_bf16(ka1, aq[1][1], sB, 0, 0, 0);
      float a0 = exp2f(sA[0]), a1 = exp2f(sA[1]), a2 = exp2f(sA[2]), a3 = exp2f(sA[3]);
      float b0 = exp2f(sB[0]), b1 = exp2f(sB[1]), b2 = exp2f(sB[2]), b3 = exp2f(sB[3]);
      lsum0 += (a0 + a1) + (a2 + a3);
      lsum1 += (b0 + b1) + (b2 + b3);
      int ww = sub & 1, off = (sub >> 1) * 4;
      pA[ww][off + 0] = bf16_of(a0); pA[ww][off + 1] = bf16_of(a1);
      pA[ww][off + 2] = bf16_of(a2); pA[ww][off + 3] = bf16_of(a3);
      pB[ww][off + 0] = bf16_of(b0); pB[ww][off + 1] = bf16_of(b1);
      pB[ww][off + 2] = bf16_of(b2); pB[ww][off + 3] = bf16_of(b3);
    }
    __builtin_amdgcn_s_setprio(1);
#pragma unroll
    for (int tt = 0; tt < 3; tt++) {
#pragma unroll
      for (int w2 = 0; w2 < 2; w2++) {
        short8 va = *reinterpret_cast<const short8*>(&Vc[(tt * 16 + t) * KPAD + w2 * 32 + kf]);
        OaccA[tt] = __builtin_amdgcn_mfma_f32_16x16x32_bf16(va, pA[w2], OaccA[tt], 0, 0, 0);
        OaccB[tt] = __builtin_amdgcn_mfma_f32_16x16x32_bf16(va, pB[w2], OaccB[tt], 0, 0, 0);
      }
    }
    __builtin_amdgcn_s_setprio(0);
    if (j + 1 < NJ) commit(cur ^ 1);
    __syncthreads();
  }

  // epilogue
  lsum0 += __shfl_xor(lsum0, 16); lsum0 += __shfl_xor(lsum0, 32);
  lsum1 += __shfl_xor(lsum1, 16); lsum1 += __shfl_xor(lsum1, 32);

  float* Of = (float*)smem;
#pragma unroll
  for (int tt = 0; tt < 3; tt++)
#pragma unroll
    for (int r = 0; r < 4; r++) {
      Of[(w * 32 + t) * 52 + tt * 16 + g * 4 + r] = OaccA[tt][r];
      Of[(w * 32 + 16 + t) * 52 + tt * 16 + g * 4 + r] = OaccB[tt][r];
    }
  if (lane < 16) {
    size_t lb = (size_t)(split * NBH + bhv) * S_ + q0w + lane;
    AccL[lb] = lsum0;
    AccL[lb + 16] = lsum1;
  }
  __syncthreads();
  short* CtxP = Ctx + (size_t)split * NBH * S_ * 48;
  size_t obase = bh + it * 128;
  for (int task = tid; task < 768; task += 256) {
    int row = task / 6, c8 = task % 6;
    const float* src = &Of[row * 52 + c8 * 8];
    short8 o;
#pragma unroll
    for (int i = 0; i < 8; i++) o[i] = bf16_of(src[i]);
    *reinterpret_cast<short8*>(&CtxP[(obase + row) * 48 + c8 * 8]) = o;
  }
}

// ---------------- output projection + fused 4-way split-merge + fused point_proj ----------------

__global__ __launch_bounds__(512) void out_gemm(
    const short* __restrict__ Ctx, const float* __restrict__ AccL,
    const short* __restrict__ Wot, const float* __restrict__ bo,
    const float* __restrict__ Wpo, const float* __restrict__ bpo,
    float* __restrict__ Out) {
  const size_t CTXSZ = (size_t)NBH * S_ * 48;
  int m0 = blockIdx.x * 64;
  int tid = threadIdx.x;
  int b = m0 >> 11, sbase = m0 & 2047;

  if (blockIdx.y == 4) {
    int row = tid >> 3, hh = tid & 7;
    int m = m0 + row, s = sbase + row;
    size_t rowO = (size_t)(b * 8 + hh) * S_ + s;
    float l = 0.f;
#pragma unroll
    for (int sp = 0; sp < NSPLIT; sp++) l += AccL[(size_t)sp * NBH * S_ + rowO];
    float inv = 1.0f / l;
    float a0 = 0.f, a1 = 0.f, a2 = 0.f;
#pragma unroll
    for (int half = 0; half < 2; half++) {
      float sum[8] = {};
#pragma unroll
      for (int sp = 0; sp < NSPLIT; sp++) {
        short8 v = *reinterpret_cast<const short8*>(&Ctx[sp * CTXSZ + rowO * 48 + 32 + half * 8]);
#pragma unroll
        for (int c = 0; c < 8; c++) sum[c] += f_of_bf16(v[c]);
      }
#pragma unroll
      for (int c = 0; c < 8; c++) {
        float val = sum[c] * inv;
        int j = hh * 16 + half * 8 + c;
        a0 += val * Wpo[j * 3 + 0];
        a1 += val * Wpo[j * 3 + 1];
        a2 += val * Wpo[j * 3 + 2];
      }
    }
    a0 += __shfl_xor(a0, 1); a0 += __shfl_xor(a0, 2); a0 += __shfl_xor(a0, 4);
    a1 += __shfl_xor(a1, 1); a1 += __shfl_xor(a1, 2); a1 += __shfl_xor(a1, 4);
    a2 += __shfl_xor(a2, 1); a2 += __shfl_xor(a2, 2); a2 += __shfl_xor(a2, 4);
    if (hh == 0) {
      float* po = Out + (size_t)MTOT * 256;
      po[(size_t)m * 3 + 0] = a0 + bpo[0];
      po[(size_t)m * 3 + 1] = a1 + bpo[1];
      po[(size_t)m * 3 + 2] = a2 + bpo[2];
    }
    return;
  }

  __shared__ __align__(16) short As[64 * 136];
  __shared__ __align__(16) short Bs[64 * 136];
  int n0 = blockIdx.y * 64;
  int lane = tid & 63, w = tid >> 6;
  int t = lane & 15, g = lane >> 4, kf = g * 8;
  int wm = w & 3, wn = w >> 2;
  f32x4 acc[2] = {};
  int srow = tid >> 3, skc = (tid & 7) * 16;
  for (int ph = 0; ph < 2; ph++) {
    int k0 = ph * 128;
    __syncthreads();
    {
      int kg = k0 + skc;
      int hh = kg >> 5, d0 = kg & 31;
      size_t rowO = (size_t)(b * 8 + hh) * S_ + sbase + srow;
      float l = 0.f;
#pragma unroll
      for (int sp = 0; sp < NSPLIT; sp++) l += AccL[(size_t)sp * NBH * S_ + rowO];
      float inv = 1.0f / l;
#pragma unroll
      for (int half = 0; half < 2; half++) {
        float sum[8] = {};
#pragma unroll
        for (int sp = 0; sp < NSPLIT; sp++) {
          short8 a = *reinterpret_cast<const short8*>(&Ctx[sp * CTXSZ + rowO * 48 + d0 + half * 8]);
#pragma unroll
          for (int c = 0; c < 8; c++) sum[c] += f_of_bf16(a[c]);
        }
        short8 o;
#pragma unroll
        for (int c = 0; c < 8; c++) o[c] = bf16_of(sum[c] * inv);
        *reinterpret_cast<short8*>(&As[srow * 136 + skc + half * 8]) = o;
      }
      *reinterpret_cast<uint4*>(&Bs[srow * 136 + skc]) =
          *reinterpret_cast<const uint4*>(&Wot[(size_t)(n0 + srow) * 256 + kg]);
      *reinterpret_cast<uint4*>(&Bs[srow * 136 + skc + 8]) =
          *reinterpret_cast<const uint4*>(&Wot[(size_t)(n0 + srow) * 256 + kg + 8]);
    }
    __syncthreads();
#pragma unroll
    for (int kk = 0; kk < 4; kk++) {
      short8 a = *reinterpret_cast<const short8*>(&As[(wm * 16 + t) * 136 + kk * 32 + kf]);
#pragma unroll
      for (int jj = 0; jj < 2; jj++) {
        short8 bb = *reinterpret_cast<const short8*>(&Bs[(wn * 32 + jj * 16 + t) * 136 + kk * 32 + kf]);
        acc[jj] = __builtin_amdgcn_mfma_f32_16x16x32_bf16(a, bb, acc[jj], 0, 0, 0);
      }
    }
  }
#pragma unroll
  for (int jj = 0; jj < 2; jj++)
#pragma unroll
    for (int r = 0; r < 4; r++) {
      int mrow = m0 + wm * 16 + g * 4 + r;
      int n = n0 + wn * 32 + jj * 16 + t;
      Out[(size_t)mrow * 256 + n] = acc[jj][r] + bo[n];
    }
}

// ---------------- launch ----------------

extern "C" void kernel_launch(void* const* d_in, const int* in_sizes, int n_in,
                              void* d_out, int out_size, void* d_ws, size_t ws_size,
                              hipStream_t stream) {
  const float* seq    = (const float*)d_in[0];
  const float* coords = (const float*)d_in[1];
  const int*   mask   = (const int*)d_in[3];
  const float* Wq  = (const float*)d_in[4];
  const float* bq  = (const float*)d_in[5];
  const float* Wk  = (const float*)d_in[6];
  const float* bk  = (const float*)d_in[7];
  const float* Wv  = (const float*)d_in[8];
  const float* bv  = (const float*)d_in[9];
  const float* Wpq = (const float*)d_in[10];
  const float* bpq = (const float*)d_in[11];
  const float* Wpk = (const float*)d_in[12];
  const float* bpk = (const float*)d_in[13];
  const float* Wo  = (const float*)d_in[14];
  const float* bo  = (const float*)d_in[15];
  const float* Wpo = (const float*)d_in[16];
  const float* bpo = (const float*)d_in[17];
  float* out = (float*)d_out;

  char* ws = (char*)d_ws;
  short* Wqkv_t = (short*)ws; ws += 768 * 256 * 2;
  short* Wo_t   = (short*)ws; ws += 256 * 256 * 2;
  short* Xb     = (short*)ws; ws += (size_t)MTOT * D_ * 2;
  short* Qa     = (short*)ws; ws += (size_t)NBH * S_ * AUGQ * 2;
  short* Ka     = (short*)ws; ws += (size_t)NBH * S_ * AUGQ * 2;
  short* VaT    = (short*)ws; ws += (size_t)NBH * 48 * S_ * 2;
  short* Ctx    = (short*)ws; ws += (size_t)NSPLIT * NBH * S_ * 48 * 2;
  float* AccL   = (float*)ws; ws += (size_t)NSPLIT * NBH * S_ * 4;

  prep_all<<<960, 256, 0, stream>>>(Wq, Wk, Wv, Wo, seq, coords, mask,
                                    Wpq, bpq, Wpk, bpk,
                                    Wqkv_t, Wo_t, Xb, Qa, Ka, VaT);
  qkv_gemm<<<dim3(64, 12), 256, 0, stream>>>(Xb, Wqkv_t, bq, bk, bv, Qa, Ka, VaT);
  attn<<<1024, 256, 0, stream>>>(Qa, Ka, VaT, Ctx, AccL);
  out_gemm<<<dim3(64, 5), 512, 0, stream>>>(Ctx, AccL, Wo_t, bo, Wpo, bpo, out);
}